// Round 1
// baseline (658.610 us; speedup 1.0000x reference)
//
#include <hip/hip_runtime.h>
#include <hip/hip_bf16.h>
#include <math.h>
#include <stdint.h>

#define N_NODES 50000
#define N_EDGES 800000
#define N_GRAPHS 256
#define F_IN 64
#define F_HID 128
#define N_HID 512
#define N_OUT 256

// ---------------------------------------------------------------------------
// K1: in-degree count (edges only; self-loop added analytically later)
__global__ void count_deg(const int* __restrict__ ei, int* __restrict__ indeg) {
    int e = blockIdx.x * blockDim.x + threadIdx.x;
    if (e < N_EDGES) atomicAdd(&indeg[ei[N_EDGES + e]], 1);
}

// ---------------------------------------------------------------------------
// K2: single-block exclusive scan of indeg -> offsets, plus dis = rsqrt(deg+1)
__global__ void scan_deg(const int* __restrict__ indeg, int* __restrict__ offsets,
                         float* __restrict__ dis) {
    __shared__ int buf[1024];
    __shared__ int carry;
    int tid = threadIdx.x;
    if (tid == 0) carry = 0;
    __syncthreads();
    for (int base = 0; base < N_NODES; base += 1024) {
        int i = base + tid;
        int v = (i < N_NODES) ? indeg[i] : 0;
        if (i < N_NODES) dis[i] = rsqrtf((float)(v + 1));
        buf[tid] = v;
        __syncthreads();
        for (int off = 1; off < 1024; off <<= 1) {
            int t = (tid >= off) ? buf[tid - off] : 0;
            __syncthreads();
            buf[tid] += t;
            __syncthreads();
        }
        int excl = carry + buf[tid] - v;
        if (i < N_NODES) offsets[i] = excl;
        __syncthreads();                 // all threads done reading carry/buf
        if (tid == 1023) carry += buf[1023];
        __syncthreads();                 // carry visible for next chunk
    }
    if (tid == 0) offsets[N_NODES] = carry;
}

// ---------------------------------------------------------------------------
// K3: scatter edges into CSR (by dst), with precomputed edge weight
__global__ void build_csr(const int* __restrict__ ei, const int* __restrict__ offsets,
                          int* __restrict__ cursor, const float* __restrict__ dis,
                          int* __restrict__ csr_src, float* __restrict__ csr_w) {
    int e = blockIdx.x * blockDim.x + threadIdx.x;
    if (e < N_EDGES) {
        int s = ei[e];
        int d = ei[N_EDGES + e];
        int pos = atomicAdd(&cursor[d], 1);
        int idx = offsets[d] + pos;
        csr_src[idx] = s;
        csr_w[idx] = dis[s] * dis[d];
    }
}

// ---------------------------------------------------------------------------
// K4: C[M,128] = A[M,K] @ W[K,128].  64x64 tiles, 16x16 threads, 4x4/thread.
template <int K>
__global__ __launch_bounds__(256) void gemm_nodes(const float* __restrict__ A,
                                                  const float* __restrict__ W,
                                                  float* __restrict__ out, int M) {
    const int BM = 64, BN = 64, KC = 32;
    __shared__ float As[KC][BM + 1];   // +1 pad: conflict-free transposed store
    __shared__ float Bs[KC][BN];
    int tid = threadIdx.x;
    int tx = tid % 16, ty = tid / 16;
    int row0 = blockIdx.x * BM;
    int col0 = blockIdx.y * BN;
    float acc[4][4] = {};
    for (int k0 = 0; k0 < K; k0 += KC) {
        {   // A tile: coalesced along K, store transposed
            int k = tid % KC;
            int m0 = tid / KC;          // 0..7
            for (int mm = m0; mm < BM; mm += 8) {
                int r = row0 + mm;
                As[k][mm] = (r < M) ? A[(size_t)r * K + k0 + k] : 0.f;
            }
        }
        {   // B tile: coalesced along N
            int n = tid % BN;
            int kk0 = tid / BN;         // 0..3
            for (int kk = kk0; kk < KC; kk += 4)
                Bs[kk][n] = W[(size_t)(k0 + kk) * 128 + col0 + n];
        }
        __syncthreads();
#pragma unroll
        for (int k = 0; k < KC; ++k) {
            float a[4], b[4];
#pragma unroll
            for (int i = 0; i < 4; ++i) a[i] = As[k][ty * 4 + i];
#pragma unroll
            for (int j = 0; j < 4; ++j) b[j] = Bs[k][tx * 4 + j];
#pragma unroll
            for (int i = 0; i < 4; ++i)
#pragma unroll
                for (int j = 0; j < 4; ++j) acc[i][j] += a[i] * b[j];
        }
        __syncthreads();
    }
#pragma unroll
    for (int i = 0; i < 4; ++i) {
        int r = row0 + ty * 4 + i;
        if (r < M) {
            float4 v = make_float4(acc[i][0], acc[i][1], acc[i][2], acc[i][3]);
            *(float4*)&out[(size_t)r * 128 + col0 + tx * 4] = v;
        }
    }
}

// ---------------------------------------------------------------------------
// K5: per-node CSR gather-aggregate + self-loop + bias (+ relu)
template <bool RELU>
__global__ __launch_bounds__(128) void aggregate(const float* __restrict__ h,
                                                 const int* __restrict__ offsets,
                                                 const int* __restrict__ csr_src,
                                                 const float* __restrict__ csr_w,
                                                 const float* __restrict__ dis,
                                                 const float* __restrict__ bias,
                                                 float* __restrict__ out) {
    int i = blockIdx.x;
    int f = threadIdx.x;              // 0..127
    float dii = dis[i];
    float acc = dii * dii * h[(size_t)i * F_HID + f];   // self loop: norm = 1/deg
    int s0 = offsets[i], s1 = offsets[i + 1];
    for (int j = s0; j < s1; ++j) {
        int s = csr_src[j];
        float w = csr_w[j];
        acc += w * h[(size_t)s * F_HID + f];
    }
    acc += bias[f];
    out[(size_t)i * F_HID + f] = RELU ? fmaxf(acc, 0.f) : acc;
}

// ---------------------------------------------------------------------------
// K6: mean-pool (batch is sorted -> register-accumulate 16 nodes, flush on change)
__global__ __launch_bounds__(128) void pool16(const float* __restrict__ h,
                                              const int* __restrict__ batch,
                                              float* __restrict__ g_acc,
                                              float* __restrict__ g_cnt) {
    const int NB = 16;
    int base = blockIdx.x * NB;
    int f = threadIdx.x;
    float acc = 0.f;
    int cur = -1, cnt = 0;
    for (int n = 0; n < NB; ++n) {
        int i = base + n;
        if (i >= N_NODES) break;
        int b = batch[i];
        if (b != cur) {
            if (cur >= 0) {
                atomicAdd(&g_acc[(size_t)cur * F_HID + f], acc);
                if (f == 0) atomicAdd(&g_cnt[cur], (float)cnt);
            }
            cur = b; acc = 0.f; cnt = 0;
        }
        acc += h[(size_t)i * F_HID + f];
        cnt++;
    }
    if (cur >= 0) {
        atomicAdd(&g_acc[(size_t)cur * F_HID + f], acc);
        if (f == 0) atomicAdd(&g_cnt[cur], (float)cnt);
    }
}

// ---------------------------------------------------------------------------
// K7: g_hid = relu((g_acc/cnt) @ Wm1 + bm1)   [256,128]@[128,512]
__global__ __launch_bounds__(512) void mlp1(const float* __restrict__ g_acc,
                                            const float* __restrict__ g_cnt,
                                            const float* __restrict__ Wm1,
                                            const float* __restrict__ bm1,
                                            float* __restrict__ g_hid) {
    __shared__ float row[F_HID];
    int g = blockIdx.x;
    int t = threadIdx.x;              // 0..511
    if (t < F_HID) {
        float c = g_cnt[g];
        row[t] = g_acc[(size_t)g * F_HID + t] / fmaxf(c, 1.0f);
    }
    __syncthreads();
    float acc = bm1[t];
    for (int k = 0; k < F_HID; ++k) acc += row[k] * Wm1[(size_t)k * N_HID + t];
    g_hid[(size_t)g * N_HID + t] = fmaxf(acc, 0.f);
}

// K8: out = g_hid @ Wm2 + bm2   [256,512]@[512,256]
__global__ __launch_bounds__(256) void mlp2(const float* __restrict__ g_hid,
                                            const float* __restrict__ Wm2,
                                            const float* __restrict__ bm2,
                                            float* __restrict__ out) {
    __shared__ float row[N_HID];
    int g = blockIdx.x;
    int t = threadIdx.x;              // 0..255
    row[t] = g_hid[(size_t)g * N_HID + t];
    row[t + 256] = g_hid[(size_t)g * N_HID + t + 256];
    __syncthreads();
    float acc = bm2[t];
    for (int k = 0; k < N_HID; ++k) acc += row[k] * Wm2[(size_t)k * N_OUT + t];
    out[(size_t)g * N_OUT + t] = acc;
}

// ---------------------------------------------------------------------------
extern "C" void kernel_launch(void* const* d_in, const int* in_sizes, int n_in,
                              void* d_out, int out_size, void* d_ws, size_t ws_size,
                              hipStream_t stream) {
    const float* x   = (const float*)d_in[0];
    const int* ei    = (const int*)d_in[1];     // [2, E] int32
    const int* batch = (const int*)d_in[2];
    const float* W0 = (const float*)d_in[3];  const float* b0 = (const float*)d_in[4];
    const float* W1 = (const float*)d_in[5];  const float* b1 = (const float*)d_in[6];
    const float* W2 = (const float*)d_in[7];  const float* b2 = (const float*)d_in[8];
    const float* Wm1 = (const float*)d_in[9];  const float* bm1 = (const float*)d_in[10];
    const float* Wm2 = (const float*)d_in[11]; const float* bm2 = (const float*)d_in[12];

    // bump allocator on d_ws, 256B-aligned slots
    char* p = (char*)d_ws;
    auto alloc = [&](size_t bytes) -> char* {
        char* r = p;
        p += (bytes + 255) & ~(size_t)255;
        return r;
    };
    // zero-init region (contiguous in allocation order)
    int*   indeg  = (int*)alloc(N_NODES * 4);
    int*   cursor = (int*)alloc(N_NODES * 4);
    float* g_acc  = (float*)alloc((size_t)N_GRAPHS * F_HID * 4);
    float* g_cnt  = (float*)alloc(N_GRAPHS * 4);
    size_t zero_bytes = (size_t)(p - (char*)indeg);
    // rest
    int*   offsets = (int*)alloc((N_NODES + 1) * 4);
    float* dis     = (float*)alloc(N_NODES * 4);
    int*   csr_src = (int*)alloc((size_t)N_EDGES * 4);
    float* csr_w   = (float*)alloc((size_t)N_EDGES * 4);
    float* h_a     = (float*)alloc((size_t)N_NODES * F_HID * 4);
    float* h_b     = (float*)alloc((size_t)N_NODES * F_HID * 4);
    float* g_hid   = (float*)alloc((size_t)N_GRAPHS * N_HID * 4);
    (void)ws_size; (void)in_sizes; (void)n_in; (void)out_size;

    hipMemsetAsync(indeg, 0, zero_bytes, stream);

    count_deg<<<(N_EDGES + 255) / 256, 256, 0, stream>>>(ei, indeg);
    scan_deg<<<1, 1024, 0, stream>>>(indeg, offsets, dis);
    build_csr<<<(N_EDGES + 255) / 256, 256, 0, stream>>>(ei, offsets, cursor, dis,
                                                         csr_src, csr_w);

    dim3 gg((N_NODES + 63) / 64, 2);
    // layer 0
    gemm_nodes<F_IN><<<gg, 256, 0, stream>>>(x, W0, h_a, N_NODES);
    aggregate<true><<<N_NODES, 128, 0, stream>>>(h_a, offsets, csr_src, csr_w, dis, b0, h_b);
    // layer 1
    gemm_nodes<F_HID><<<gg, 256, 0, stream>>>(h_b, W1, h_a, N_NODES);
    aggregate<true><<<N_NODES, 128, 0, stream>>>(h_a, offsets, csr_src, csr_w, dis, b1, h_b);
    // layer 2
    gemm_nodes<F_HID><<<gg, 256, 0, stream>>>(h_b, W2, h_a, N_NODES);
    aggregate<false><<<N_NODES, 128, 0, stream>>>(h_a, offsets, csr_src, csr_w, dis, b2, h_b);

    // pool + MLP
    pool16<<<(N_NODES + 15) / 16, 128, 0, stream>>>(h_b, batch, g_acc, g_cnt);
    mlp1<<<N_GRAPHS, N_HID, 0, stream>>>(g_acc, g_cnt, Wm1, bm1, g_hid);
    mlp2<<<N_GRAPHS, N_OUT, 0, stream>>>(g_hid, Wm2, bm2, (float*)d_out);
}

// Round 2
// 577.616 us; speedup vs baseline: 1.1402x; 1.1402x over previous
//
#include <hip/hip_runtime.h>
#include <hip/hip_bf16.h>
#include <math.h>
#include <stdint.h>

#define N_NODES 50000
#define N_EDGES 800000
#define N_GRAPHS 256
#define F_IN 64
#define F_HID 128
#define N_HID 512
#define N_OUT 256

#define SCAN_B 256
#define SCAN_NBLK ((N_NODES + SCAN_B - 1) / SCAN_B)   // 196

// ---------------------------------------------------------------------------
// K1: in-degree count (edges only; self-loop added analytically later)
__global__ void count_deg(const int* __restrict__ ei, int* __restrict__ indeg) {
    int e = blockIdx.x * blockDim.x + threadIdx.x;
    if (e < N_EDGES) atomicAdd(&indeg[ei[N_EDGES + e]], 1);
}

// ---------------------------------------------------------------------------
// K2a: per-block reduction of indeg chunks -> blockSums
__global__ __launch_bounds__(SCAN_B) void scan_partial(const int* __restrict__ indeg,
                                                       int* __restrict__ blockSums) {
    __shared__ int sdata[SCAN_B];
    int i = blockIdx.x * SCAN_B + threadIdx.x;
    sdata[threadIdx.x] = (i < N_NODES) ? indeg[i] : 0;
    __syncthreads();
    for (int off = SCAN_B / 2; off > 0; off >>= 1) {
        if (threadIdx.x < off) sdata[threadIdx.x] += sdata[threadIdx.x + off];
        __syncthreads();
    }
    if (threadIdx.x == 0) blockSums[blockIdx.x] = sdata[0];
}

// K2b: single tiny block: exclusive scan of blockSums (SCAN_NBLK <= 256)
__global__ __launch_bounds__(SCAN_B) void scan_block_sums(int* __restrict__ blockSums) {
    __shared__ int buf[SCAN_B];
    int tid = threadIdx.x;
    int v = (tid < SCAN_NBLK) ? blockSums[tid] : 0;
    buf[tid] = v;
    __syncthreads();
    for (int off = 1; off < SCAN_B; off <<= 1) {
        int t = (tid >= off) ? buf[tid - off] : 0;
        __syncthreads();
        buf[tid] += t;
        __syncthreads();
    }
    if (tid < SCAN_NBLK) blockSums[tid] = buf[tid] - v;   // exclusive
}

// K2c: per-block exclusive scan + block offset -> offsets; also dis = rsqrt(deg+1)
__global__ __launch_bounds__(SCAN_B) void scan_final(const int* __restrict__ indeg,
                                                     const int* __restrict__ blockSums,
                                                     int* __restrict__ offsets,
                                                     float* __restrict__ dis) {
    __shared__ int buf[SCAN_B];
    int tid = threadIdx.x;
    int i = blockIdx.x * SCAN_B + tid;
    int v = (i < N_NODES) ? indeg[i] : 0;
    if (i < N_NODES) dis[i] = rsqrtf((float)(v + 1));
    buf[tid] = v;
    __syncthreads();
    for (int off = 1; off < SCAN_B; off <<= 1) {
        int t = (tid >= off) ? buf[tid - off] : 0;
        __syncthreads();
        buf[tid] += t;
        __syncthreads();
    }
    if (i < N_NODES) offsets[i] = blockSums[blockIdx.x] + buf[tid] - v;
    if (i == 0) offsets[N_NODES] = N_EDGES;   // total is statically known
}

// ---------------------------------------------------------------------------
// K3: scatter edges into CSR (by dst), with precomputed edge weight
__global__ void build_csr(const int* __restrict__ ei, const int* __restrict__ offsets,
                          int* __restrict__ cursor, const float* __restrict__ dis,
                          int* __restrict__ csr_src, float* __restrict__ csr_w) {
    int e = blockIdx.x * blockDim.x + threadIdx.x;
    if (e < N_EDGES) {
        int s = ei[e];
        int d = ei[N_EDGES + e];
        int pos = atomicAdd(&cursor[d], 1);
        int idx = offsets[d] + pos;
        csr_src[idx] = s;
        csr_w[idx] = dis[s] * dis[d];
    }
}

// ---------------------------------------------------------------------------
// K4: C[M,128] = A[M,K] @ W[K,128].  64x64 tiles, 16x16 threads, 4x4/thread.
template <int K>
__global__ __launch_bounds__(256) void gemm_nodes(const float* __restrict__ A,
                                                  const float* __restrict__ W,
                                                  float* __restrict__ out, int M) {
    const int BM = 64, BN = 64, KC = 32;
    __shared__ float As[KC][BM + 1];   // +1 pad: conflict-free transposed store
    __shared__ float Bs[KC][BN];
    int tid = threadIdx.x;
    int tx = tid % 16, ty = tid / 16;
    int row0 = blockIdx.x * BM;
    int col0 = blockIdx.y * BN;
    float acc[4][4] = {};
    for (int k0 = 0; k0 < K; k0 += KC) {
        {   // A tile: coalesced along K, store transposed
            int k = tid % KC;
            int m0 = tid / KC;          // 0..7
            for (int mm = m0; mm < BM; mm += 8) {
                int r = row0 + mm;
                As[k][mm] = (r < M) ? A[(size_t)r * K + k0 + k] : 0.f;
            }
        }
        {   // B tile: coalesced along N
            int n = tid % BN;
            int kk0 = tid / BN;         // 0..3
            for (int kk = kk0; kk < KC; kk += 4)
                Bs[kk][n] = W[(size_t)(k0 + kk) * 128 + col0 + n];
        }
        __syncthreads();
#pragma unroll
        for (int k = 0; k < KC; ++k) {
            float a[4], b[4];
#pragma unroll
            for (int i = 0; i < 4; ++i) a[i] = As[k][ty * 4 + i];
#pragma unroll
            for (int j = 0; j < 4; ++j) b[j] = Bs[k][tx * 4 + j];
#pragma unroll
            for (int i = 0; i < 4; ++i)
#pragma unroll
                for (int j = 0; j < 4; ++j) acc[i][j] += a[i] * b[j];
        }
        __syncthreads();
    }
#pragma unroll
    for (int i = 0; i < 4; ++i) {
        int r = row0 + ty * 4 + i;
        if (r < M) {
            float4 v = make_float4(acc[i][0], acc[i][1], acc[i][2], acc[i][3]);
            *(float4*)&out[(size_t)r * 128 + col0 + tx * 4] = v;
        }
    }
}

// ---------------------------------------------------------------------------
// K5: per-node CSR gather-aggregate + self-loop + bias (+ relu)
template <bool RELU>
__global__ __launch_bounds__(128) void aggregate(const float* __restrict__ h,
                                                 const int* __restrict__ offsets,
                                                 const int* __restrict__ csr_src,
                                                 const float* __restrict__ csr_w,
                                                 const float* __restrict__ dis,
                                                 const float* __restrict__ bias,
                                                 float* __restrict__ out) {
    int i = blockIdx.x;
    int f = threadIdx.x;              // 0..127
    float dii = dis[i];
    float acc = dii * dii * h[(size_t)i * F_HID + f];   // self loop: norm = 1/deg
    int s0 = offsets[i], s1 = offsets[i + 1];
    for (int j = s0; j < s1; ++j) {
        int s = csr_src[j];
        float w = csr_w[j];
        acc += w * h[(size_t)s * F_HID + f];
    }
    acc += bias[f];
    out[(size_t)i * F_HID + f] = RELU ? fmaxf(acc, 0.f) : acc;
}

// ---------------------------------------------------------------------------
// K6: mean-pool (batch is sorted -> register-accumulate 16 nodes, flush on change)
__global__ __launch_bounds__(128) void pool16(const float* __restrict__ h,
                                              const int* __restrict__ batch,
                                              float* __restrict__ g_acc,
                                              float* __restrict__ g_cnt) {
    const int NB = 16;
    int base = blockIdx.x * NB;
    int f = threadIdx.x;
    float acc = 0.f;
    int cur = -1, cnt = 0;
    for (int n = 0; n < NB; ++n) {
        int i = base + n;
        if (i >= N_NODES) break;
        int b = batch[i];
        if (b != cur) {
            if (cur >= 0) {
                atomicAdd(&g_acc[(size_t)cur * F_HID + f], acc);
                if (f == 0) atomicAdd(&g_cnt[cur], (float)cnt);
            }
            cur = b; acc = 0.f; cnt = 0;
        }
        acc += h[(size_t)i * F_HID + f];
        cnt++;
    }
    if (cur >= 0) {
        atomicAdd(&g_acc[(size_t)cur * F_HID + f], acc);
        if (f == 0) atomicAdd(&g_cnt[cur], (float)cnt);
    }
}

// ---------------------------------------------------------------------------
// K7: g_hid = relu((g_acc/cnt) @ Wm1 + bm1)   [256,128]@[128,512]
__global__ __launch_bounds__(512) void mlp1(const float* __restrict__ g_acc,
                                            const float* __restrict__ g_cnt,
                                            const float* __restrict__ Wm1,
                                            const float* __restrict__ bm1,
                                            float* __restrict__ g_hid) {
    __shared__ float row[F_HID];
    int g = blockIdx.x;
    int t = threadIdx.x;              // 0..511
    if (t < F_HID) {
        float c = g_cnt[g];
        row[t] = g_acc[(size_t)g * F_HID + t] / fmaxf(c, 1.0f);
    }
    __syncthreads();
    float acc = bm1[t];
    for (int k = 0; k < F_HID; ++k) acc += row[k] * Wm1[(size_t)k * N_HID + t];
    g_hid[(size_t)g * N_HID + t] = fmaxf(acc, 0.f);
}

// K8: out = g_hid @ Wm2 + bm2   [256,512]@[512,256]
__global__ __launch_bounds__(256) void mlp2(const float* __restrict__ g_hid,
                                            const float* __restrict__ Wm2,
                                            const float* __restrict__ bm2,
                                            float* __restrict__ out) {
    __shared__ float row[N_HID];
    int g = blockIdx.x;
    int t = threadIdx.x;              // 0..255
    row[t] = g_hid[(size_t)g * N_HID + t];
    row[t + 256] = g_hid[(size_t)g * N_HID + t + 256];
    __syncthreads();
    float acc = bm2[t];
    for (int k = 0; k < N_HID; ++k) acc += row[k] * Wm2[(size_t)k * N_OUT + t];
    out[(size_t)g * N_OUT + t] = acc;
}

// ---------------------------------------------------------------------------
extern "C" void kernel_launch(void* const* d_in, const int* in_sizes, int n_in,
                              void* d_out, int out_size, void* d_ws, size_t ws_size,
                              hipStream_t stream) {
    const float* x   = (const float*)d_in[0];
    const int* ei    = (const int*)d_in[1];     // [2, E] int32
    const int* batch = (const int*)d_in[2];
    const float* W0 = (const float*)d_in[3];  const float* b0 = (const float*)d_in[4];
    const float* W1 = (const float*)d_in[5];  const float* b1 = (const float*)d_in[6];
    const float* W2 = (const float*)d_in[7];  const float* b2 = (const float*)d_in[8];
    const float* Wm1 = (const float*)d_in[9];  const float* bm1 = (const float*)d_in[10];
    const float* Wm2 = (const float*)d_in[11]; const float* bm2 = (const float*)d_in[12];

    // bump allocator on d_ws, 256B-aligned slots
    char* p = (char*)d_ws;
    auto alloc = [&](size_t bytes) -> char* {
        char* r = p;
        p += (bytes + 255) & ~(size_t)255;
        return r;
    };
    // zero-init region (contiguous in allocation order)
    int*   indeg  = (int*)alloc(N_NODES * 4);
    int*   cursor = (int*)alloc(N_NODES * 4);
    float* g_acc  = (float*)alloc((size_t)N_GRAPHS * F_HID * 4);
    float* g_cnt  = (float*)alloc(N_GRAPHS * 4);
    size_t zero_bytes = (size_t)(p - (char*)indeg);
    // rest
    int*   blockSums = (int*)alloc(SCAN_NBLK * 4);
    int*   offsets = (int*)alloc((N_NODES + 1) * 4);
    float* dis     = (float*)alloc(N_NODES * 4);
    int*   csr_src = (int*)alloc((size_t)N_EDGES * 4);
    float* csr_w   = (float*)alloc((size_t)N_EDGES * 4);
    float* h_a     = (float*)alloc((size_t)N_NODES * F_HID * 4);
    float* h_b     = (float*)alloc((size_t)N_NODES * F_HID * 4);
    float* g_hid   = (float*)alloc((size_t)N_GRAPHS * N_HID * 4);
    (void)ws_size; (void)in_sizes; (void)n_in; (void)out_size;

    hipMemsetAsync(indeg, 0, zero_bytes, stream);

    count_deg<<<(N_EDGES + 255) / 256, 256, 0, stream>>>(ei, indeg);
    scan_partial<<<SCAN_NBLK, SCAN_B, 0, stream>>>(indeg, blockSums);
    scan_block_sums<<<1, SCAN_B, 0, stream>>>(blockSums);
    scan_final<<<SCAN_NBLK, SCAN_B, 0, stream>>>(indeg, blockSums, offsets, dis);
    build_csr<<<(N_EDGES + 255) / 256, 256, 0, stream>>>(ei, offsets, cursor, dis,
                                                         csr_src, csr_w);

    dim3 gg((N_NODES + 63) / 64, 2);
    // layer 0
    gemm_nodes<F_IN><<<gg, 256, 0, stream>>>(x, W0, h_a, N_NODES);
    aggregate<true><<<N_NODES, 128, 0, stream>>>(h_a, offsets, csr_src, csr_w, dis, b0, h_b);
    // layer 1
    gemm_nodes<F_HID><<<gg, 256, 0, stream>>>(h_b, W1, h_a, N_NODES);
    aggregate<true><<<N_NODES, 128, 0, stream>>>(h_a, offsets, csr_src, csr_w, dis, b1, h_b);
    // layer 2
    gemm_nodes<F_HID><<<gg, 256, 0, stream>>>(h_b, W2, h_a, N_NODES);
    aggregate<false><<<N_NODES, 128, 0, stream>>>(h_a, offsets, csr_src, csr_w, dis, b2, h_b);

    // pool + MLP
    pool16<<<(N_NODES + 15) / 16, 128, 0, stream>>>(h_b, batch, g_acc, g_cnt);
    mlp1<<<N_GRAPHS, N_HID, 0, stream>>>(g_acc, g_cnt, Wm1, bm1, g_hid);
    mlp2<<<N_GRAPHS, N_OUT, 0, stream>>>(g_hid, Wm2, bm2, (float*)d_out);
}

// Round 3
// 541.754 us; speedup vs baseline: 1.2157x; 1.0662x over previous
//
#include <hip/hip_runtime.h>
#include <hip/hip_bf16.h>
#include <math.h>
#include <stdint.h>

#define N_NODES 50000
#define N_EDGES 800000
#define N_GRAPHS 256
#define F_IN 64
#define F_HID 128
#define N_HID 512
#define N_OUT 256

#define SCAN_B 256
#define SCAN_NBLK ((N_NODES + SCAN_B - 1) / SCAN_B)   // 196

// ---------------------------------------------------------------------------
// K1: in-degree count (edges only; self-loop added analytically later)
__global__ void count_deg(const int* __restrict__ ei, int* __restrict__ indeg) {
    int e = blockIdx.x * blockDim.x + threadIdx.x;
    if (e < N_EDGES) atomicAdd(&indeg[ei[N_EDGES + e]], 1);
}

// ---------------------------------------------------------------------------
// K2a: per-block reduction of indeg chunks -> blockSums
__global__ __launch_bounds__(SCAN_B) void scan_partial(const int* __restrict__ indeg,
                                                       int* __restrict__ blockSums) {
    __shared__ int sdata[SCAN_B];
    int i = blockIdx.x * SCAN_B + threadIdx.x;
    sdata[threadIdx.x] = (i < N_NODES) ? indeg[i] : 0;
    __syncthreads();
    for (int off = SCAN_B / 2; off > 0; off >>= 1) {
        if (threadIdx.x < off) sdata[threadIdx.x] += sdata[threadIdx.x + off];
        __syncthreads();
    }
    if (threadIdx.x == 0) blockSums[blockIdx.x] = sdata[0];
}

// K2b: single tiny block: exclusive scan of blockSums (SCAN_NBLK <= 256)
__global__ __launch_bounds__(SCAN_B) void scan_block_sums(int* __restrict__ blockSums) {
    __shared__ int buf[SCAN_B];
    int tid = threadIdx.x;
    int v = (tid < SCAN_NBLK) ? blockSums[tid] : 0;
    buf[tid] = v;
    __syncthreads();
    for (int off = 1; off < SCAN_B; off <<= 1) {
        int t = (tid >= off) ? buf[tid - off] : 0;
        __syncthreads();
        buf[tid] += t;
        __syncthreads();
    }
    if (tid < SCAN_NBLK) blockSums[tid] = buf[tid] - v;   // exclusive
}

// K2c: per-block exclusive scan + block offset -> offsets; also dis = rsqrt(deg+1)
__global__ __launch_bounds__(SCAN_B) void scan_final(const int* __restrict__ indeg,
                                                     const int* __restrict__ blockSums,
                                                     int* __restrict__ offsets,
                                                     float* __restrict__ dis) {
    __shared__ int buf[SCAN_B];
    int tid = threadIdx.x;
    int i = blockIdx.x * SCAN_B + tid;
    int v = (i < N_NODES) ? indeg[i] : 0;
    if (i < N_NODES) dis[i] = rsqrtf((float)(v + 1));
    buf[tid] = v;
    __syncthreads();
    for (int off = 1; off < SCAN_B; off <<= 1) {
        int t = (tid >= off) ? buf[tid - off] : 0;
        __syncthreads();
        buf[tid] += t;
        __syncthreads();
    }
    if (i < N_NODES) offsets[i] = blockSums[blockIdx.x] + buf[tid] - v;
    if (i == 0) offsets[N_NODES] = N_EDGES;   // total is statically known
}

// ---------------------------------------------------------------------------
// K3: scatter edges into CSR (by dst), with precomputed edge weight
__global__ void build_csr(const int* __restrict__ ei, const int* __restrict__ offsets,
                          int* __restrict__ cursor, const float* __restrict__ dis,
                          int* __restrict__ csr_src, float* __restrict__ csr_w) {
    int e = blockIdx.x * blockDim.x + threadIdx.x;
    if (e < N_EDGES) {
        int s = ei[e];
        int d = ei[N_EDGES + e];
        int pos = atomicAdd(&cursor[d], 1);
        int idx = offsets[d] + pos;
        csr_src[idx] = s;
        csr_w[idx] = dis[s] * dis[d];
    }
}

// ---------------------------------------------------------------------------
// K4: C[M,128] = A[M,K] @ W[K,128].  128x128 block tile, 256 thr, 8x8/thread.
// Split-column/row mapping (tx*4 and 64+tx*4) keeps LDS reads conflict-free.
template <int K, bool BIASRELU>
__global__ __launch_bounds__(256) void gemm128(const float* __restrict__ A,
                                               const float* __restrict__ W,
                                               const float* __restrict__ bias,
                                               float* __restrict__ out, int M) {
    const int BM = 128, KC = 32;
    __shared__ float As[KC][BM + 4];
    __shared__ float Bs[KC][128];
    int tid = threadIdx.x;
    int tx = tid % 16, ty = (tid / 16) % 16;
    int row0 = blockIdx.x * BM;
    float acc[8][8] = {};
    for (int k0 = 0; k0 < K; k0 += KC) {
        {   // A tile: coalesced along K (32 lanes = one row chunk), store transposed
            int k = tid % KC;
            int m0 = tid / KC;          // 0..7
#pragma unroll
            for (int mm = m0; mm < BM; mm += 8) {
                int r = row0 + mm;
                As[k][mm] = (r < M) ? A[(size_t)r * K + k0 + k] : 0.f;
            }
        }
        {   // B tile: coalesced along N
            int n = tid % 128;
            int kk0 = tid / 128;        // 0..1
#pragma unroll
            for (int kk = kk0; kk < KC; kk += 2)
                Bs[kk][n] = W[(size_t)(k0 + kk) * 128 + n];
        }
        __syncthreads();
#pragma unroll
        for (int k = 0; k < KC; ++k) {
            float a[8], b[8];
#pragma unroll
            for (int i = 0; i < 4; ++i) {
                a[i]     = As[k][ty * 4 + i];
                a[i + 4] = As[k][64 + ty * 4 + i];
                b[i]     = Bs[k][tx * 4 + i];
                b[i + 4] = Bs[k][64 + tx * 4 + i];
            }
#pragma unroll
            for (int i = 0; i < 8; ++i)
#pragma unroll
                for (int j = 0; j < 8; ++j) acc[i][j] += a[i] * b[j];
        }
        __syncthreads();
    }
    int c0 = tx * 4, c1 = 64 + tx * 4;
#pragma unroll
    for (int i = 0; i < 8; ++i) {
        int r = row0 + (i < 4 ? ty * 4 + i : 64 + ty * 4 + (i - 4));
        if (r < M) {
            float4 v0 = make_float4(acc[i][0], acc[i][1], acc[i][2], acc[i][3]);
            float4 v1 = make_float4(acc[i][4], acc[i][5], acc[i][6], acc[i][7]);
            if (BIASRELU) {
                v0.x = fmaxf(v0.x + bias[c0], 0.f);  v0.y = fmaxf(v0.y + bias[c0+1], 0.f);
                v0.z = fmaxf(v0.z + bias[c0+2], 0.f); v0.w = fmaxf(v0.w + bias[c0+3], 0.f);
                v1.x = fmaxf(v1.x + bias[c1], 0.f);  v1.y = fmaxf(v1.y + bias[c1+1], 0.f);
                v1.z = fmaxf(v1.z + bias[c1+2], 0.f); v1.w = fmaxf(v1.w + bias[c1+3], 0.f);
            }
            *(float4*)&out[(size_t)r * 128 + c0] = v0;
            *(float4*)&out[(size_t)r * 128 + c1] = v1;
        }
    }
}

// ---------------------------------------------------------------------------
// K5a: F=128 aggregate. One wave per node, lane holds float2. Edge loop
// unrolled x8/x4 for memory-level parallelism (latency-bound gather).
template <bool RELU>
__global__ __launch_bounds__(256) void aggregate128(const float* __restrict__ h,
                                                    const int* __restrict__ offsets,
                                                    const int* __restrict__ csr_src,
                                                    const float* __restrict__ csr_w,
                                                    const float* __restrict__ dis,
                                                    const float* __restrict__ bias,
                                                    float* __restrict__ out) {
    int wave = threadIdx.x >> 6;
    int lane = threadIdx.x & 63;
    int i = blockIdx.x * 4 + wave;
    if (i >= N_NODES) return;
    const float2* h2 = (const float2*)h;
    float dii = dis[i];
    float2 self = h2[(size_t)i * 64 + lane];
    float ax = dii * dii * self.x;
    float ay = dii * dii * self.y;
    int j = offsets[i], s1 = offsets[i + 1];
    for (; j + 8 <= s1; j += 8) {
        int   s[8];  float w[8];  float2 r[8];
#pragma unroll
        for (int u = 0; u < 8; ++u) { s[u] = csr_src[j + u]; w[u] = csr_w[j + u]; }
#pragma unroll
        for (int u = 0; u < 8; ++u) r[u] = h2[(size_t)s[u] * 64 + lane];
#pragma unroll
        for (int u = 0; u < 8; ++u) { ax += w[u] * r[u].x; ay += w[u] * r[u].y; }
    }
    for (; j + 4 <= s1; j += 4) {
        int   s[4];  float w[4];  float2 r[4];
#pragma unroll
        for (int u = 0; u < 4; ++u) { s[u] = csr_src[j + u]; w[u] = csr_w[j + u]; }
#pragma unroll
        for (int u = 0; u < 4; ++u) r[u] = h2[(size_t)s[u] * 64 + lane];
#pragma unroll
        for (int u = 0; u < 4; ++u) { ax += w[u] * r[u].x; ay += w[u] * r[u].y; }
    }
    for (; j < s1; ++j) {
        int s = csr_src[j]; float w = csr_w[j];
        float2 r = h2[(size_t)s * 64 + lane];
        ax += w * r.x; ay += w * r.y;
    }
    float2 b = ((const float2*)bias)[lane];
    ax += b.x; ay += b.y;
    if (RELU) { ax = fmaxf(ax, 0.f); ay = fmaxf(ay, 0.f); }
    float2 o; o.x = ax; o.y = ay;
    ((float2*)out)[(size_t)i * 64 + lane] = o;
}

// K5b: F=64 aggregate of raw x (layer-0 reorder: Â(XW) == (ÂX)W).
// One wave per node, lane = feature. No bias/relu (applied in GEMM epilogue).
__global__ __launch_bounds__(256) void aggregate_x(const float* __restrict__ x,
                                                   const int* __restrict__ offsets,
                                                   const int* __restrict__ csr_src,
                                                   const float* __restrict__ csr_w,
                                                   const float* __restrict__ dis,
                                                   float* __restrict__ out) {
    int wave = threadIdx.x >> 6;
    int lane = threadIdx.x & 63;
    int i = blockIdx.x * 4 + wave;
    if (i >= N_NODES) return;
    float dii = dis[i];
    float acc = dii * dii * x[(size_t)i * 64 + lane];
    int j = offsets[i], s1 = offsets[i + 1];
    for (; j + 8 <= s1; j += 8) {
        int s[8]; float w[8]; float r[8];
#pragma unroll
        for (int u = 0; u < 8; ++u) { s[u] = csr_src[j + u]; w[u] = csr_w[j + u]; }
#pragma unroll
        for (int u = 0; u < 8; ++u) r[u] = x[(size_t)s[u] * 64 + lane];
#pragma unroll
        for (int u = 0; u < 8; ++u) acc += w[u] * r[u];
    }
    for (; j + 4 <= s1; j += 4) {
        int s[4]; float w[4]; float r[4];
#pragma unroll
        for (int u = 0; u < 4; ++u) { s[u] = csr_src[j + u]; w[u] = csr_w[j + u]; }
#pragma unroll
        for (int u = 0; u < 4; ++u) r[u] = x[(size_t)s[u] * 64 + lane];
#pragma unroll
        for (int u = 0; u < 4; ++u) acc += w[u] * r[u];
    }
    for (; j < s1; ++j) acc += csr_w[j] * x[(size_t)csr_src[j] * 64 + lane];
    out[(size_t)i * 64 + lane] = acc;
}

// ---------------------------------------------------------------------------
// K6: mean-pool (batch is sorted -> register-accumulate 16 nodes, flush on change)
__global__ __launch_bounds__(128) void pool16(const float* __restrict__ h,
                                              const int* __restrict__ batch,
                                              float* __restrict__ g_acc,
                                              float* __restrict__ g_cnt) {
    const int NB = 16;
    int base = blockIdx.x * NB;
    int f = threadIdx.x;
    float acc = 0.f;
    int cur = -1, cnt = 0;
    for (int n = 0; n < NB; ++n) {
        int i = base + n;
        if (i >= N_NODES) break;
        int b = batch[i];
        if (b != cur) {
            if (cur >= 0) {
                atomicAdd(&g_acc[(size_t)cur * F_HID + f], acc);
                if (f == 0) atomicAdd(&g_cnt[cur], (float)cnt);
            }
            cur = b; acc = 0.f; cnt = 0;
        }
        acc += h[(size_t)i * F_HID + f];
        cnt++;
    }
    if (cur >= 0) {
        atomicAdd(&g_acc[(size_t)cur * F_HID + f], acc);
        if (f == 0) atomicAdd(&g_cnt[cur], (float)cnt);
    }
}

// ---------------------------------------------------------------------------
// K7: g_hid = relu((g_acc/cnt) @ Wm1 + bm1)   [256,128]@[128,512]
__global__ __launch_bounds__(512) void mlp1(const float* __restrict__ g_acc,
                                            const float* __restrict__ g_cnt,
                                            const float* __restrict__ Wm1,
                                            const float* __restrict__ bm1,
                                            float* __restrict__ g_hid) {
    __shared__ float row[F_HID];
    int g = blockIdx.x;
    int t = threadIdx.x;              // 0..511
    if (t < F_HID) {
        float c = g_cnt[g];
        row[t] = g_acc[(size_t)g * F_HID + t] / fmaxf(c, 1.0f);
    }
    __syncthreads();
    float acc = bm1[t];
    for (int k = 0; k < F_HID; ++k) acc += row[k] * Wm1[(size_t)k * N_HID + t];
    g_hid[(size_t)g * N_HID + t] = fmaxf(acc, 0.f);
}

// K8: out = g_hid @ Wm2 + bm2   [256,512]@[512,256]
__global__ __launch_bounds__(256) void mlp2(const float* __restrict__ g_hid,
                                            const float* __restrict__ Wm2,
                                            const float* __restrict__ bm2,
                                            float* __restrict__ out) {
    __shared__ float row[N_HID];
    int g = blockIdx.x;
    int t = threadIdx.x;              // 0..255
    row[t] = g_hid[(size_t)g * N_HID + t];
    row[t + 256] = g_hid[(size_t)g * N_HID + t + 256];
    __syncthreads();
    float acc = bm2[t];
    for (int k = 0; k < N_HID; ++k) acc += row[k] * Wm2[(size_t)k * N_OUT + t];
    out[(size_t)g * N_OUT + t] = acc;
}

// ---------------------------------------------------------------------------
extern "C" void kernel_launch(void* const* d_in, const int* in_sizes, int n_in,
                              void* d_out, int out_size, void* d_ws, size_t ws_size,
                              hipStream_t stream) {
    const float* x   = (const float*)d_in[0];
    const int* ei    = (const int*)d_in[1];     // [2, E] int32
    const int* batch = (const int*)d_in[2];
    const float* W0 = (const float*)d_in[3];  const float* b0 = (const float*)d_in[4];
    const float* W1 = (const float*)d_in[5];  const float* b1 = (const float*)d_in[6];
    const float* W2 = (const float*)d_in[7];  const float* b2 = (const float*)d_in[8];
    const float* Wm1 = (const float*)d_in[9];  const float* bm1 = (const float*)d_in[10];
    const float* Wm2 = (const float*)d_in[11]; const float* bm2 = (const float*)d_in[12];

    // bump allocator on d_ws, 256B-aligned slots
    char* p = (char*)d_ws;
    auto alloc = [&](size_t bytes) -> char* {
        char* r = p;
        p += (bytes + 255) & ~(size_t)255;
        return r;
    };
    // zero-init region (contiguous in allocation order)
    int*   indeg  = (int*)alloc(N_NODES * 4);
    int*   cursor = (int*)alloc(N_NODES * 4);
    float* g_acc  = (float*)alloc((size_t)N_GRAPHS * F_HID * 4);
    float* g_cnt  = (float*)alloc(N_GRAPHS * 4);
    size_t zero_bytes = (size_t)(p - (char*)indeg);
    // rest
    int*   blockSums = (int*)alloc(SCAN_NBLK * 4);
    int*   offsets = (int*)alloc((N_NODES + 1) * 4);
    float* dis     = (float*)alloc(N_NODES * 4);
    int*   csr_src = (int*)alloc((size_t)N_EDGES * 4);
    float* csr_w   = (float*)alloc((size_t)N_EDGES * 4);
    float* ax      = (float*)alloc((size_t)N_NODES * F_IN * 4);
    float* h_a     = (float*)alloc((size_t)N_NODES * F_HID * 4);
    float* h_tmp   = (float*)alloc((size_t)N_NODES * F_HID * 4);
    float* h_b     = (float*)alloc((size_t)N_NODES * F_HID * 4);
    float* g_hid   = (float*)alloc((size_t)N_GRAPHS * N_HID * 4);
    (void)ws_size; (void)in_sizes; (void)n_in; (void)out_size;

    hipMemsetAsync(indeg, 0, zero_bytes, stream);

    count_deg<<<(N_EDGES + 255) / 256, 256, 0, stream>>>(ei, indeg);
    scan_partial<<<SCAN_NBLK, SCAN_B, 0, stream>>>(indeg, blockSums);
    scan_block_sums<<<1, SCAN_B, 0, stream>>>(blockSums);
    scan_final<<<SCAN_NBLK, SCAN_B, 0, stream>>>(indeg, blockSums, offsets, dis);
    build_csr<<<(N_EDGES + 255) / 256, 256, 0, stream>>>(ei, offsets, cursor, dis,
                                                         csr_src, csr_w);

    int agg_grid = (N_NODES + 3) / 4;          // 4 nodes (waves) per block
    int gemm_grid = (N_NODES + 127) / 128;

    // layer 0 (reordered): ax = Â x; h_a = relu(ax @ W0 + b0)
    aggregate_x<<<agg_grid, 256, 0, stream>>>(x, offsets, csr_src, csr_w, dis, ax);
    gemm128<F_IN, true><<<gemm_grid, 256, 0, stream>>>(ax, W0, b0, h_a, N_NODES);
    // layer 1: h_b = relu(Â (h_a @ W1) + b1)
    gemm128<F_HID, false><<<gemm_grid, 256, 0, stream>>>(h_a, W1, nullptr, h_tmp, N_NODES);
    aggregate128<true><<<agg_grid, 256, 0, stream>>>(h_tmp, offsets, csr_src, csr_w, dis, b1, h_b);
    // layer 2: h_a = Â (h_b @ W2) + b2
    gemm128<F_HID, false><<<gemm_grid, 256, 0, stream>>>(h_b, W2, nullptr, h_tmp, N_NODES);
    aggregate128<false><<<agg_grid, 256, 0, stream>>>(h_tmp, offsets, csr_src, csr_w, dis, b2, h_a);

    // pool + MLP
    pool16<<<(N_NODES + 15) / 16, 128, 0, stream>>>(h_a, batch, g_acc, g_cnt);
    mlp1<<<N_GRAPHS, N_HID, 0, stream>>>(g_acc, g_cnt, Wm1, bm1, g_hid);
    mlp2<<<N_GRAPHS, N_OUT, 0, stream>>>(g_hid, Wm2, bm2, (float*)d_out);
}

// Round 4
// 497.922 us; speedup vs baseline: 1.3227x; 1.0880x over previous
//
#include <hip/hip_runtime.h>
#include <hip/hip_bf16.h>
#include <math.h>
#include <stdint.h>

#define N_NODES 50000
#define N_EDGES 800000
#define N_GRAPHS 256
#define F_IN 64
#define F_HID 128
#define N_HID 512
#define N_OUT 256

#define SCAN_B 256
#define SCAN_NBLK ((N_NODES + SCAN_B - 1) / SCAN_B)   // 196

// ---------------------------------------------------------------------------
// K1: in-degree count (edges only; self-loop added analytically later)
__global__ void count_deg(const int* __restrict__ ei, int* __restrict__ indeg) {
    int e = blockIdx.x * blockDim.x + threadIdx.x;
    if (e < N_EDGES) atomicAdd(&indeg[ei[N_EDGES + e]], 1);
}

// ---------------------------------------------------------------------------
// K2a: per-block reduction of indeg chunks -> blockSums
__global__ __launch_bounds__(SCAN_B) void scan_partial(const int* __restrict__ indeg,
                                                       int* __restrict__ blockSums) {
    __shared__ int sdata[SCAN_B];
    int i = blockIdx.x * SCAN_B + threadIdx.x;
    sdata[threadIdx.x] = (i < N_NODES) ? indeg[i] : 0;
    __syncthreads();
    for (int off = SCAN_B / 2; off > 0; off >>= 1) {
        if (threadIdx.x < off) sdata[threadIdx.x] += sdata[threadIdx.x + off];
        __syncthreads();
    }
    if (threadIdx.x == 0) blockSums[blockIdx.x] = sdata[0];
}

// K2b: single tiny block: exclusive scan of blockSums (SCAN_NBLK <= 256)
__global__ __launch_bounds__(SCAN_B) void scan_block_sums(int* __restrict__ blockSums) {
    __shared__ int buf[SCAN_B];
    int tid = threadIdx.x;
    int v = (tid < SCAN_NBLK) ? blockSums[tid] : 0;
    buf[tid] = v;
    __syncthreads();
    for (int off = 1; off < SCAN_B; off <<= 1) {
        int t = (tid >= off) ? buf[tid - off] : 0;
        __syncthreads();
        buf[tid] += t;
        __syncthreads();
    }
    if (tid < SCAN_NBLK) blockSums[tid] = buf[tid] - v;   // exclusive
}

// K2c: per-block exclusive scan + block offset -> offsets; also dis = rsqrt(deg+1)
__global__ __launch_bounds__(SCAN_B) void scan_final(const int* __restrict__ indeg,
                                                     const int* __restrict__ blockSums,
                                                     int* __restrict__ offsets,
                                                     float* __restrict__ dis) {
    __shared__ int buf[SCAN_B];
    int tid = threadIdx.x;
    int i = blockIdx.x * SCAN_B + tid;
    int v = (i < N_NODES) ? indeg[i] : 0;
    if (i < N_NODES) dis[i] = rsqrtf((float)(v + 1));
    buf[tid] = v;
    __syncthreads();
    for (int off = 1; off < SCAN_B; off <<= 1) {
        int t = (tid >= off) ? buf[tid - off] : 0;
        __syncthreads();
        buf[tid] += t;
        __syncthreads();
    }
    if (i < N_NODES) offsets[i] = blockSums[blockIdx.x] + buf[tid] - v;
    if (i == 0) offsets[N_NODES] = N_EDGES;   // total is statically known
}

// ---------------------------------------------------------------------------
// K3: scatter edges into CSR (by dst), with precomputed edge weight
__global__ void build_csr(const int* __restrict__ ei, const int* __restrict__ offsets,
                          int* __restrict__ cursor, const float* __restrict__ dis,
                          int* __restrict__ csr_src, float* __restrict__ csr_w) {
    int e = blockIdx.x * blockDim.x + threadIdx.x;
    if (e < N_EDGES) {
        int s = ei[e];
        int d = ei[N_EDGES + e];
        int pos = atomicAdd(&cursor[d], 1);
        int idx = offsets[d] + pos;
        csr_src[idx] = s;
        csr_w[idx] = dis[s] * dis[d];
    }
}

// ---------------------------------------------------------------------------
// K4: C[M,128] = A[M,K] @ W[K,128].  64x128 tile, 256 thr, 4x8/thread.
// As row-major [m][k+1-pad]: staging writes conflict-free (consecutive banks),
// reads are same-address broadcasts across tx. Bs[k][n]: b128 conflict-free.
template <int K, bool BIASRELU>
__global__ __launch_bounds__(256) void gemm64x128(const float* __restrict__ A,
                                                  const float* __restrict__ W,
                                                  const float* __restrict__ bias,
                                                  float* __restrict__ out, int M) {
    const int BM = 64, KC = 32;
    __shared__ float As[BM][KC + 1];   // 8.4 KB
    __shared__ float Bs[KC][128];      // 16 KB
    int tid = threadIdx.x;
    int tx = tid % 16;                 // cols tx*4.. and 64+tx*4..
    int ty = tid / 16;                 // rows ty*4..ty*4+3
    int row0 = blockIdx.x * BM;
    float acc[4][8] = {};
    for (int k0 = 0; k0 < K; k0 += KC) {
        {   // A tile: lanes sweep k (coalesced 128B/row-chunk), natural layout
            int k = tid % KC;
            int m0 = tid / KC;         // 0..7
#pragma unroll
            for (int mm = m0; mm < BM; mm += 8) {
                int r = row0 + mm;
                As[mm][k] = (r < M) ? A[(size_t)r * K + k0 + k] : 0.f;
            }
        }
        {   // B tile: coalesced along N
            int n = tid % 128;
            int kk0 = tid / 128;       // 0..1
#pragma unroll
            for (int kk = kk0; kk < KC; kk += 2)
                Bs[kk][n] = W[(size_t)(k0 + kk) * 128 + n];
        }
        __syncthreads();
#pragma unroll
        for (int k = 0; k < KC; ++k) {
            float a[4], b[8];
#pragma unroll
            for (int i = 0; i < 4; ++i) a[i] = As[ty * 4 + i][k];
#pragma unroll
            for (int j = 0; j < 4; ++j) {
                b[j]     = Bs[k][tx * 4 + j];
                b[j + 4] = Bs[k][64 + tx * 4 + j];
            }
#pragma unroll
            for (int i = 0; i < 4; ++i)
#pragma unroll
                for (int j = 0; j < 8; ++j) acc[i][j] += a[i] * b[j];
        }
        __syncthreads();
    }
    int c0 = tx * 4, c1 = 64 + tx * 4;
#pragma unroll
    for (int i = 0; i < 4; ++i) {
        int r = row0 + ty * 4 + i;
        if (r < M) {
            float4 v0 = make_float4(acc[i][0], acc[i][1], acc[i][2], acc[i][3]);
            float4 v1 = make_float4(acc[i][4], acc[i][5], acc[i][6], acc[i][7]);
            if (BIASRELU) {
                v0.x = fmaxf(v0.x + bias[c0], 0.f);   v0.y = fmaxf(v0.y + bias[c0+1], 0.f);
                v0.z = fmaxf(v0.z + bias[c0+2], 0.f); v0.w = fmaxf(v0.w + bias[c0+3], 0.f);
                v1.x = fmaxf(v1.x + bias[c1], 0.f);   v1.y = fmaxf(v1.y + bias[c1+1], 0.f);
                v1.z = fmaxf(v1.z + bias[c1+2], 0.f); v1.w = fmaxf(v1.w + bias[c1+3], 0.f);
            }
            *(float4*)&out[(size_t)r * 128 + c0] = v0;
            *(float4*)&out[(size_t)r * 128 + c1] = v1;
        }
    }
}

// ---------------------------------------------------------------------------
// K5a: F=128 aggregate. One wave per node, lane holds float2. Edge loop
// unrolled x8/x4 for memory-level parallelism (latency-bound gather).
template <bool RELU>
__global__ __launch_bounds__(256) void aggregate128(const float* __restrict__ h,
                                                    const int* __restrict__ offsets,
                                                    const int* __restrict__ csr_src,
                                                    const float* __restrict__ csr_w,
                                                    const float* __restrict__ dis,
                                                    const float* __restrict__ bias,
                                                    float* __restrict__ out) {
    int wave = threadIdx.x >> 6;
    int lane = threadIdx.x & 63;
    int i = blockIdx.x * 4 + wave;
    if (i >= N_NODES) return;
    const float2* h2 = (const float2*)h;
    float dii = dis[i];
    float2 self = h2[(size_t)i * 64 + lane];
    float ax = dii * dii * self.x;
    float ay = dii * dii * self.y;
    int j = offsets[i], s1 = offsets[i + 1];
    for (; j + 8 <= s1; j += 8) {
        int   s[8];  float w[8];  float2 r[8];
#pragma unroll
        for (int u = 0; u < 8; ++u) { s[u] = csr_src[j + u]; w[u] = csr_w[j + u]; }
#pragma unroll
        for (int u = 0; u < 8; ++u) r[u] = h2[(size_t)s[u] * 64 + lane];
#pragma unroll
        for (int u = 0; u < 8; ++u) { ax += w[u] * r[u].x; ay += w[u] * r[u].y; }
    }
    for (; j + 4 <= s1; j += 4) {
        int   s[4];  float w[4];  float2 r[4];
#pragma unroll
        for (int u = 0; u < 4; ++u) { s[u] = csr_src[j + u]; w[u] = csr_w[j + u]; }
#pragma unroll
        for (int u = 0; u < 4; ++u) r[u] = h2[(size_t)s[u] * 64 + lane];
#pragma unroll
        for (int u = 0; u < 4; ++u) { ax += w[u] * r[u].x; ay += w[u] * r[u].y; }
    }
    for (; j < s1; ++j) {
        int s = csr_src[j]; float w = csr_w[j];
        float2 r = h2[(size_t)s * 64 + lane];
        ax += w * r.x; ay += w * r.y;
    }
    float2 b = ((const float2*)bias)[lane];
    ax += b.x; ay += b.y;
    if (RELU) { ax = fmaxf(ax, 0.f); ay = fmaxf(ay, 0.f); }
    float2 o; o.x = ax; o.y = ay;
    ((float2*)out)[(size_t)i * 64 + lane] = o;
}

// K5b: F=64 aggregate of raw x (layer-0 reorder: Â(XW) == (ÂX)W).
// One wave per node, lane = feature. No bias/relu (applied in GEMM epilogue).
__global__ __launch_bounds__(256) void aggregate_x(const float* __restrict__ x,
                                                   const int* __restrict__ offsets,
                                                   const int* __restrict__ csr_src,
                                                   const float* __restrict__ csr_w,
                                                   const float* __restrict__ dis,
                                                   float* __restrict__ out) {
    int wave = threadIdx.x >> 6;
    int lane = threadIdx.x & 63;
    int i = blockIdx.x * 4 + wave;
    if (i >= N_NODES) return;
    float dii = dis[i];
    float acc = dii * dii * x[(size_t)i * 64 + lane];
    int j = offsets[i], s1 = offsets[i + 1];
    for (; j + 8 <= s1; j += 8) {
        int s[8]; float w[8]; float r[8];
#pragma unroll
        for (int u = 0; u < 8; ++u) { s[u] = csr_src[j + u]; w[u] = csr_w[j + u]; }
#pragma unroll
        for (int u = 0; u < 8; ++u) r[u] = x[(size_t)s[u] * 64 + lane];
#pragma unroll
        for (int u = 0; u < 8; ++u) acc += w[u] * r[u];
    }
    for (; j + 4 <= s1; j += 4) {
        int s[4]; float w[4]; float r[4];
#pragma unroll
        for (int u = 0; u < 4; ++u) { s[u] = csr_src[j + u]; w[u] = csr_w[j + u]; }
#pragma unroll
        for (int u = 0; u < 4; ++u) r[u] = x[(size_t)s[u] * 64 + lane];
#pragma unroll
        for (int u = 0; u < 4; ++u) acc += w[u] * r[u];
    }
    for (; j < s1; ++j) acc += csr_w[j] * x[(size_t)csr_src[j] * 64 + lane];
    out[(size_t)i * 64 + lane] = acc;
}

// ---------------------------------------------------------------------------
// K6: mean-pool (batch is sorted -> register-accumulate 16 nodes, flush on change)
__global__ __launch_bounds__(128) void pool16(const float* __restrict__ h,
                                              const int* __restrict__ batch,
                                              float* __restrict__ g_acc,
                                              float* __restrict__ g_cnt) {
    const int NB = 16;
    int base = blockIdx.x * NB;
    int f = threadIdx.x;
    float acc = 0.f;
    int cur = -1, cnt = 0;
    for (int n = 0; n < NB; ++n) {
        int i = base + n;
        if (i >= N_NODES) break;
        int b = batch[i];
        if (b != cur) {
            if (cur >= 0) {
                atomicAdd(&g_acc[(size_t)cur * F_HID + f], acc);
                if (f == 0) atomicAdd(&g_cnt[cur], (float)cnt);
            }
            cur = b; acc = 0.f; cnt = 0;
        }
        acc += h[(size_t)i * F_HID + f];
        cnt++;
    }
    if (cur >= 0) {
        atomicAdd(&g_acc[(size_t)cur * F_HID + f], acc);
        if (f == 0) atomicAdd(&g_cnt[cur], (float)cnt);
    }
}

// ---------------------------------------------------------------------------
// K7: g_hid = relu((g_acc/cnt) @ Wm1 + bm1)   [256,128]@[128,512]
__global__ __launch_bounds__(512) void mlp1(const float* __restrict__ g_acc,
                                            const float* __restrict__ g_cnt,
                                            const float* __restrict__ Wm1,
                                            const float* __restrict__ bm1,
                                            float* __restrict__ g_hid) {
    __shared__ float row[F_HID];
    int g = blockIdx.x;
    int t = threadIdx.x;              // 0..511
    if (t < F_HID) {
        float c = g_cnt[g];
        row[t] = g_acc[(size_t)g * F_HID + t] / fmaxf(c, 1.0f);
    }
    __syncthreads();
    float acc = bm1[t];
    for (int k = 0; k < F_HID; ++k) acc += row[k] * Wm1[(size_t)k * N_HID + t];
    g_hid[(size_t)g * N_HID + t] = fmaxf(acc, 0.f);
}

// K8: out = g_hid @ Wm2 + bm2   [256,512]@[512,256]
__global__ __launch_bounds__(256) void mlp2(const float* __restrict__ g_hid,
                                            const float* __restrict__ Wm2,
                                            const float* __restrict__ bm2,
                                            float* __restrict__ out) {
    __shared__ float row[N_HID];
    int g = blockIdx.x;
    int t = threadIdx.x;              // 0..255
    row[t] = g_hid[(size_t)g * N_HID + t];
    row[t + 256] = g_hid[(size_t)g * N_HID + t + 256];
    __syncthreads();
    float acc = bm2[t];
    for (int k = 0; k < N_HID; ++k) acc += row[k] * Wm2[(size_t)k * N_OUT + t];
    out[(size_t)g * N_OUT + t] = acc;
}

// ---------------------------------------------------------------------------
extern "C" void kernel_launch(void* const* d_in, const int* in_sizes, int n_in,
                              void* d_out, int out_size, void* d_ws, size_t ws_size,
                              hipStream_t stream) {
    const float* x   = (const float*)d_in[0];
    const int* ei    = (const int*)d_in[1];     // [2, E] int32
    const int* batch = (const int*)d_in[2];
    const float* W0 = (const float*)d_in[3];  const float* b0 = (const float*)d_in[4];
    const float* W1 = (const float*)d_in[5];  const float* b1 = (const float*)d_in[6];
    const float* W2 = (const float*)d_in[7];  const float* b2 = (const float*)d_in[8];
    const float* Wm1 = (const float*)d_in[9];  const float* bm1 = (const float*)d_in[10];
    const float* Wm2 = (const float*)d_in[11]; const float* bm2 = (const float*)d_in[12];

    // bump allocator on d_ws, 256B-aligned slots
    char* p = (char*)d_ws;
    auto alloc = [&](size_t bytes) -> char* {
        char* r = p;
        p += (bytes + 255) & ~(size_t)255;
        return r;
    };
    // zero-init region (contiguous in allocation order)
    int*   indeg  = (int*)alloc(N_NODES * 4);
    int*   cursor = (int*)alloc(N_NODES * 4);
    float* g_acc  = (float*)alloc((size_t)N_GRAPHS * F_HID * 4);
    float* g_cnt  = (float*)alloc(N_GRAPHS * 4);
    size_t zero_bytes = (size_t)(p - (char*)indeg);
    // rest
    int*   blockSums = (int*)alloc(SCAN_NBLK * 4);
    int*   offsets = (int*)alloc((N_NODES + 1) * 4);
    float* dis     = (float*)alloc(N_NODES * 4);
    int*   csr_src = (int*)alloc((size_t)N_EDGES * 4);
    float* csr_w   = (float*)alloc((size_t)N_EDGES * 4);
    float* ax      = (float*)alloc((size_t)N_NODES * F_IN * 4);
    float* h_a     = (float*)alloc((size_t)N_NODES * F_HID * 4);
    float* h_tmp   = (float*)alloc((size_t)N_NODES * F_HID * 4);
    float* h_b     = (float*)alloc((size_t)N_NODES * F_HID * 4);
    float* g_hid   = (float*)alloc((size_t)N_GRAPHS * N_HID * 4);
    (void)ws_size; (void)in_sizes; (void)n_in; (void)out_size;

    hipMemsetAsync(indeg, 0, zero_bytes, stream);

    count_deg<<<(N_EDGES + 255) / 256, 256, 0, stream>>>(ei, indeg);
    scan_partial<<<SCAN_NBLK, SCAN_B, 0, stream>>>(indeg, blockSums);
    scan_block_sums<<<1, SCAN_B, 0, stream>>>(blockSums);
    scan_final<<<SCAN_NBLK, SCAN_B, 0, stream>>>(indeg, blockSums, offsets, dis);
    build_csr<<<(N_EDGES + 255) / 256, 256, 0, stream>>>(ei, offsets, cursor, dis,
                                                         csr_src, csr_w);

    int agg_grid = (N_NODES + 3) / 4;          // 4 nodes (waves) per block
    int gemm_grid = (N_NODES + 63) / 64;       // 782 blocks

    // layer 0 (reordered): ax = Â x; h_a = relu(ax @ W0 + b0)
    aggregate_x<<<agg_grid, 256, 0, stream>>>(x, offsets, csr_src, csr_w, dis, ax);
    gemm64x128<F_IN, true><<<gemm_grid, 256, 0, stream>>>(ax, W0, b0, h_a, N_NODES);
    // layer 1: h_b = relu(Â (h_a @ W1) + b1)
    gemm64x128<F_HID, false><<<gemm_grid, 256, 0, stream>>>(h_a, W1, nullptr, h_tmp, N_NODES);
    aggregate128<true><<<agg_grid, 256, 0, stream>>>(h_tmp, offsets, csr_src, csr_w, dis, b1, h_b);
    // layer 2: h_a = Â (h_b @ W2) + b2
    gemm64x128<F_HID, false><<<gemm_grid, 256, 0, stream>>>(h_b, W2, nullptr, h_tmp, N_NODES);
    aggregate128<false><<<agg_grid, 256, 0, stream>>>(h_tmp, offsets, csr_src, csr_w, dis, b2, h_a);

    // pool + MLP
    pool16<<<(N_NODES + 15) / 16, 128, 0, stream>>>(h_a, batch, g_acc, g_cnt);
    mlp1<<<N_GRAPHS, N_HID, 0, stream>>>(g_acc, g_cnt, Wm1, bm1, g_hid);
    mlp2<<<N_GRAPHS, N_OUT, 0, stream>>>(g_hid, Wm2, bm2, (float*)d_out);
}

// Round 5
// 455.485 us; speedup vs baseline: 1.4460x; 1.0932x over previous
//
#include <hip/hip_runtime.h>
#include <hip/hip_bf16.h>
#include <math.h>
#include <stdint.h>

#define N_NODES 50000
#define N_EDGES 800000
#define N_GRAPHS 256
#define F_IN 64
#define F_HID 128
#define N_HID 512
#define N_OUT 256

#define SCAN_B 256
#define SCAN_NBLK ((N_NODES + SCAN_B - 1) / SCAN_B)   // 196

// ---------------------------------------------------------------------------
// K1: in-degree count (edges only; self-loop added analytically later)
__global__ void count_deg(const int* __restrict__ ei, int* __restrict__ indeg) {
    int e = blockIdx.x * blockDim.x + threadIdx.x;
    if (e < N_EDGES) atomicAdd(&indeg[ei[N_EDGES + e]], 1);
}

// ---------------------------------------------------------------------------
// K2a: per-block reduction of indeg chunks -> blockSums
__global__ __launch_bounds__(SCAN_B) void scan_partial(const int* __restrict__ indeg,
                                                       int* __restrict__ blockSums) {
    __shared__ int sdata[SCAN_B];
    int i = blockIdx.x * SCAN_B + threadIdx.x;
    sdata[threadIdx.x] = (i < N_NODES) ? indeg[i] : 0;
    __syncthreads();
    for (int off = SCAN_B / 2; off > 0; off >>= 1) {
        if (threadIdx.x < off) sdata[threadIdx.x] += sdata[threadIdx.x + off];
        __syncthreads();
    }
    if (threadIdx.x == 0) blockSums[blockIdx.x] = sdata[0];
}

// K2b: single tiny block: exclusive scan of blockSums (SCAN_NBLK <= 256)
__global__ __launch_bounds__(SCAN_B) void scan_block_sums(int* __restrict__ blockSums) {
    __shared__ int buf[SCAN_B];
    int tid = threadIdx.x;
    int v = (tid < SCAN_NBLK) ? blockSums[tid] : 0;
    buf[tid] = v;
    __syncthreads();
    for (int off = 1; off < SCAN_B; off <<= 1) {
        int t = (tid >= off) ? buf[tid - off] : 0;
        __syncthreads();
        buf[tid] += t;
        __syncthreads();
    }
    if (tid < SCAN_NBLK) blockSums[tid] = buf[tid] - v;   // exclusive
}

// K2c: per-block exclusive scan + block offset -> offsets; also dis = rsqrt(deg+1)
__global__ __launch_bounds__(SCAN_B) void scan_final(const int* __restrict__ indeg,
                                                     const int* __restrict__ blockSums,
                                                     int* __restrict__ offsets,
                                                     float* __restrict__ dis) {
    __shared__ int buf[SCAN_B];
    int tid = threadIdx.x;
    int i = blockIdx.x * SCAN_B + tid;
    int v = (i < N_NODES) ? indeg[i] : 0;
    if (i < N_NODES) dis[i] = rsqrtf((float)(v + 1));
    buf[tid] = v;
    __syncthreads();
    for (int off = 1; off < SCAN_B; off <<= 1) {
        int t = (tid >= off) ? buf[tid - off] : 0;
        __syncthreads();
        buf[tid] += t;
        __syncthreads();
    }
    if (i < N_NODES) offsets[i] = blockSums[blockIdx.x] + buf[tid] - v;
    if (i == 0) offsets[N_NODES] = N_EDGES;   // total is statically known
}

// ---------------------------------------------------------------------------
// K3: scatter edges into CSR (by dst), with precomputed edge weight
__global__ void build_csr(const int* __restrict__ ei, const int* __restrict__ offsets,
                          int* __restrict__ cursor, const float* __restrict__ dis,
                          int* __restrict__ csr_src, float* __restrict__ csr_w) {
    int e = blockIdx.x * blockDim.x + threadIdx.x;
    if (e < N_EDGES) {
        int s = ei[e];
        int d = ei[N_EDGES + e];
        int pos = atomicAdd(&cursor[d], 1);
        int idx = offsets[d] + pos;
        csr_src[idx] = s;
        csr_w[idx] = dis[s] * dis[d];
    }
}

// ---------------------------------------------------------------------------
// K4: C[M,128] = A[M,K] @ W[K,128]. 64x128 tile, 128 threads, 8x8/thread.
// All LDS reads are b128 (k-vectorized). As row stride 36 floats: 16B-aligned
// and the 4 distinct broadcast rows per wave land on disjoint banks (4*ty+k).
// LDS:VALU inst ratio = 16 b128 : 256 FMA per 4 k-steps -> near VALU-bound.
template <int K, bool BIASRELU>
__global__ __launch_bounds__(128) void gemm8x8(const float* __restrict__ A,
                                               const float* __restrict__ W,
                                               const float* __restrict__ bias,
                                               float* __restrict__ out, int M) {
    const int BM = 64, KC = 32, LDA = 36;
    __shared__ float As[BM * LDA];     // 9.2 KB
    __shared__ float Bs[KC * 128];     // 16 KB
    int tid = threadIdx.x;
    int tx = tid & 15;                 // cols tx*4 and 64+tx*4
    int ty = tid >> 4;                 // 0..7; rows ty + 8*i
    int row0 = blockIdx.x * BM;
    float acc[8][8] = {};
    for (int k0 = 0; k0 < K; k0 += KC) {
        // stage A: 4 float4 per thread (coalesced 128B row-chunks)
#pragma unroll
        for (int u = 0; u < 4; ++u) {
            int f4id = tid + 128 * u;
            int m = f4id >> 3;                 // 0..63
            int ks = (f4id & 7) * 4;           // 0,4,..28
            int r = row0 + m;
            float4 v = make_float4(0.f, 0.f, 0.f, 0.f);
            if (r < M) v = *(const float4*)&A[(size_t)r * K + k0 + ks];
            *(float4*)&As[m * LDA + ks] = v;
        }
        // stage B: 8 float4 per thread
#pragma unroll
        for (int u = 0; u < 8; ++u) {
            int f4id = tid + 128 * u;
            int kk = f4id >> 5;                // 0..31
            int n4 = (f4id & 31) * 4;          // 0..124
            *(float4*)&Bs[kk * 128 + n4] = *(const float4*)&W[(size_t)(k0 + kk) * 128 + n4];
        }
        __syncthreads();
#pragma unroll
        for (int kc = 0; kc < KC; kc += 4) {
            float4 av[8], bv0[4], bv1[4];
#pragma unroll
            for (int i = 0; i < 8; ++i)
                av[i] = *(const float4*)&As[(ty + 8 * i) * LDA + kc];
#pragma unroll
            for (int q = 0; q < 4; ++q) {
                bv0[q] = *(const float4*)&Bs[(kc + q) * 128 + tx * 4];
                bv1[q] = *(const float4*)&Bs[(kc + q) * 128 + 64 + tx * 4];
            }
#pragma unroll
            for (int q = 0; q < 4; ++q) {
#pragma unroll
                for (int i = 0; i < 8; ++i) {
                    float a = ((const float*)&av[i])[q];
                    acc[i][0] += a * bv0[q].x;  acc[i][1] += a * bv0[q].y;
                    acc[i][2] += a * bv0[q].z;  acc[i][3] += a * bv0[q].w;
                    acc[i][4] += a * bv1[q].x;  acc[i][5] += a * bv1[q].y;
                    acc[i][6] += a * bv1[q].z;  acc[i][7] += a * bv1[q].w;
                }
            }
        }
        __syncthreads();
    }
    int c0 = tx * 4, c1 = 64 + tx * 4;
#pragma unroll
    for (int i = 0; i < 8; ++i) {
        int r = row0 + ty + 8 * i;
        if (r < M) {
            float4 v0 = make_float4(acc[i][0], acc[i][1], acc[i][2], acc[i][3]);
            float4 v1 = make_float4(acc[i][4], acc[i][5], acc[i][6], acc[i][7]);
            if (BIASRELU) {
                v0.x = fmaxf(v0.x + bias[c0], 0.f);   v0.y = fmaxf(v0.y + bias[c0+1], 0.f);
                v0.z = fmaxf(v0.z + bias[c0+2], 0.f); v0.w = fmaxf(v0.w + bias[c0+3], 0.f);
                v1.x = fmaxf(v1.x + bias[c1], 0.f);   v1.y = fmaxf(v1.y + bias[c1+1], 0.f);
                v1.z = fmaxf(v1.z + bias[c1+2], 0.f); v1.w = fmaxf(v1.w + bias[c1+3], 0.f);
            }
            *(float4*)&out[(size_t)r * 128 + c0] = v0;
            *(float4*)&out[(size_t)r * 128 + c1] = v1;
        }
    }
}

// ---------------------------------------------------------------------------
// K5a: F=128 aggregate. One wave per node, lane holds float2. Edge loop
// unrolled x8/x4 for memory-level parallelism (latency-bound gather).
template <bool RELU>
__global__ __launch_bounds__(256) void aggregate128(const float* __restrict__ h,
                                                    const int* __restrict__ offsets,
                                                    const int* __restrict__ csr_src,
                                                    const float* __restrict__ csr_w,
                                                    const float* __restrict__ dis,
                                                    const float* __restrict__ bias,
                                                    float* __restrict__ out) {
    int wave = threadIdx.x >> 6;
    int lane = threadIdx.x & 63;
    int i = blockIdx.x * 4 + wave;
    if (i >= N_NODES) return;
    const float2* h2 = (const float2*)h;
    float dii = dis[i];
    float2 self = h2[(size_t)i * 64 + lane];
    float ax = dii * dii * self.x;
    float ay = dii * dii * self.y;
    int j = offsets[i], s1 = offsets[i + 1];
    for (; j + 8 <= s1; j += 8) {
        int   s[8];  float w[8];  float2 r[8];
#pragma unroll
        for (int u = 0; u < 8; ++u) { s[u] = csr_src[j + u]; w[u] = csr_w[j + u]; }
#pragma unroll
        for (int u = 0; u < 8; ++u) r[u] = h2[(size_t)s[u] * 64 + lane];
#pragma unroll
        for (int u = 0; u < 8; ++u) { ax += w[u] * r[u].x; ay += w[u] * r[u].y; }
    }
    for (; j + 4 <= s1; j += 4) {
        int   s[4];  float w[4];  float2 r[4];
#pragma unroll
        for (int u = 0; u < 4; ++u) { s[u] = csr_src[j + u]; w[u] = csr_w[j + u]; }
#pragma unroll
        for (int u = 0; u < 4; ++u) r[u] = h2[(size_t)s[u] * 64 + lane];
#pragma unroll
        for (int u = 0; u < 4; ++u) { ax += w[u] * r[u].x; ay += w[u] * r[u].y; }
    }
    for (; j < s1; ++j) {
        int s = csr_src[j]; float w = csr_w[j];
        float2 r = h2[(size_t)s * 64 + lane];
        ax += w * r.x; ay += w * r.y;
    }
    float2 b = ((const float2*)bias)[lane];
    ax += b.x; ay += b.y;
    if (RELU) { ax = fmaxf(ax, 0.f); ay = fmaxf(ay, 0.f); }
    float2 o; o.x = ax; o.y = ay;
    ((float2*)out)[(size_t)i * 64 + lane] = o;
}

// K5b: F=64 aggregate of raw x (layer-0 reorder: Â(XW) == (ÂX)W).
// One wave per node, lane = feature. No bias/relu (applied in GEMM epilogue).
__global__ __launch_bounds__(256) void aggregate_x(const float* __restrict__ x,
                                                   const int* __restrict__ offsets,
                                                   const int* __restrict__ csr_src,
                                                   const float* __restrict__ csr_w,
                                                   const float* __restrict__ dis,
                                                   float* __restrict__ out) {
    int wave = threadIdx.x >> 6;
    int lane = threadIdx.x & 63;
    int i = blockIdx.x * 4 + wave;
    if (i >= N_NODES) return;
    float dii = dis[i];
    float acc = dii * dii * x[(size_t)i * 64 + lane];
    int j = offsets[i], s1 = offsets[i + 1];
    for (; j + 8 <= s1; j += 8) {
        int s[8]; float w[8]; float r[8];
#pragma unroll
        for (int u = 0; u < 8; ++u) { s[u] = csr_src[j + u]; w[u] = csr_w[j + u]; }
#pragma unroll
        for (int u = 0; u < 8; ++u) r[u] = x[(size_t)s[u] * 64 + lane];
#pragma unroll
        for (int u = 0; u < 8; ++u) acc += w[u] * r[u];
    }
    for (; j + 4 <= s1; j += 4) {
        int s[4]; float w[4]; float r[4];
#pragma unroll
        for (int u = 0; u < 4; ++u) { s[u] = csr_src[j + u]; w[u] = csr_w[j + u]; }
#pragma unroll
        for (int u = 0; u < 4; ++u) r[u] = x[(size_t)s[u] * 64 + lane];
#pragma unroll
        for (int u = 0; u < 4; ++u) acc += w[u] * r[u];
    }
    for (; j < s1; ++j) acc += csr_w[j] * x[(size_t)csr_src[j] * 64 + lane];
    out[(size_t)i * 64 + lane] = acc;
}

// ---------------------------------------------------------------------------
// K6: mean-pool (batch is sorted -> register-accumulate 16 nodes, flush on change)
__global__ __launch_bounds__(128) void pool16(const float* __restrict__ h,
                                              const int* __restrict__ batch,
                                              float* __restrict__ g_acc,
                                              float* __restrict__ g_cnt) {
    const int NB = 16;
    int base = blockIdx.x * NB;
    int f = threadIdx.x;
    float acc = 0.f;
    int cur = -1, cnt = 0;
    for (int n = 0; n < NB; ++n) {
        int i = base + n;
        if (i >= N_NODES) break;
        int b = batch[i];
        if (b != cur) {
            if (cur >= 0) {
                atomicAdd(&g_acc[(size_t)cur * F_HID + f], acc);
                if (f == 0) atomicAdd(&g_cnt[cur], (float)cnt);
            }
            cur = b; acc = 0.f; cnt = 0;
        }
        acc += h[(size_t)i * F_HID + f];
        cnt++;
    }
    if (cur >= 0) {
        atomicAdd(&g_acc[(size_t)cur * F_HID + f], acc);
        if (f == 0) atomicAdd(&g_cnt[cur], (float)cnt);
    }
}

// ---------------------------------------------------------------------------
// K7: g_hid = relu((g_acc/cnt) @ Wm1 + bm1)   [256,128]@[128,512]
__global__ __launch_bounds__(512) void mlp1(const float* __restrict__ g_acc,
                                            const float* __restrict__ g_cnt,
                                            const float* __restrict__ Wm1,
                                            const float* __restrict__ bm1,
                                            float* __restrict__ g_hid) {
    __shared__ float row[F_HID];
    int g = blockIdx.x;
    int t = threadIdx.x;              // 0..511
    if (t < F_HID) {
        float c = g_cnt[g];
        row[t] = g_acc[(size_t)g * F_HID + t] / fmaxf(c, 1.0f);
    }
    __syncthreads();
    float acc = bm1[t];
    for (int k = 0; k < F_HID; ++k) acc += row[k] * Wm1[(size_t)k * N_HID + t];
    g_hid[(size_t)g * N_HID + t] = fmaxf(acc, 0.f);
}

// K8: out = g_hid @ Wm2 + bm2   [256,512]@[512,256]
__global__ __launch_bounds__(256) void mlp2(const float* __restrict__ g_hid,
                                            const float* __restrict__ Wm2,
                                            const float* __restrict__ bm2,
                                            float* __restrict__ out) {
    __shared__ float row[N_HID];
    int g = blockIdx.x;
    int t = threadIdx.x;              // 0..255
    row[t] = g_hid[(size_t)g * N_HID + t];
    row[t + 256] = g_hid[(size_t)g * N_HID + t + 256];
    __syncthreads();
    float acc = bm2[t];
    for (int k = 0; k < N_HID; ++k) acc += row[k] * Wm2[(size_t)k * N_OUT + t];
    out[(size_t)g * N_OUT + t] = acc;
}

// ---------------------------------------------------------------------------
extern "C" void kernel_launch(void* const* d_in, const int* in_sizes, int n_in,
                              void* d_out, int out_size, void* d_ws, size_t ws_size,
                              hipStream_t stream) {
    const float* x   = (const float*)d_in[0];
    const int* ei    = (const int*)d_in[1];     // [2, E] int32
    const int* batch = (const int*)d_in[2];
    const float* W0 = (const float*)d_in[3];  const float* b0 = (const float*)d_in[4];
    const float* W1 = (const float*)d_in[5];  const float* b1 = (const float*)d_in[6];
    const float* W2 = (const float*)d_in[7];  const float* b2 = (const float*)d_in[8];
    const float* Wm1 = (const float*)d_in[9];  const float* bm1 = (const float*)d_in[10];
    const float* Wm2 = (const float*)d_in[11]; const float* bm2 = (const float*)d_in[12];

    // bump allocator on d_ws, 256B-aligned slots
    char* p = (char*)d_ws;
    auto alloc = [&](size_t bytes) -> char* {
        char* r = p;
        p += (bytes + 255) & ~(size_t)255;
        return r;
    };
    // zero-init region (contiguous in allocation order)
    int*   indeg  = (int*)alloc(N_NODES * 4);
    int*   cursor = (int*)alloc(N_NODES * 4);
    float* g_acc  = (float*)alloc((size_t)N_GRAPHS * F_HID * 4);
    float* g_cnt  = (float*)alloc(N_GRAPHS * 4);
    size_t zero_bytes = (size_t)(p - (char*)indeg);
    // rest
    int*   blockSums = (int*)alloc(SCAN_NBLK * 4);
    int*   offsets = (int*)alloc((N_NODES + 1) * 4);
    float* dis     = (float*)alloc(N_NODES * 4);
    int*   csr_src = (int*)alloc((size_t)N_EDGES * 4);
    float* csr_w   = (float*)alloc((size_t)N_EDGES * 4);
    float* ax      = (float*)alloc((size_t)N_NODES * F_IN * 4);
    float* h_a     = (float*)alloc((size_t)N_NODES * F_HID * 4);
    float* h_tmp   = (float*)alloc((size_t)N_NODES * F_HID * 4);
    float* h_b     = (float*)alloc((size_t)N_NODES * F_HID * 4);
    float* g_hid   = (float*)alloc((size_t)N_GRAPHS * N_HID * 4);
    (void)ws_size; (void)in_sizes; (void)n_in; (void)out_size;

    hipMemsetAsync(indeg, 0, zero_bytes, stream);

    count_deg<<<(N_EDGES + 255) / 256, 256, 0, stream>>>(ei, indeg);
    scan_partial<<<SCAN_NBLK, SCAN_B, 0, stream>>>(indeg, blockSums);
    scan_block_sums<<<1, SCAN_B, 0, stream>>>(blockSums);
    scan_final<<<SCAN_NBLK, SCAN_B, 0, stream>>>(indeg, blockSums, offsets, dis);
    build_csr<<<(N_EDGES + 255) / 256, 256, 0, stream>>>(ei, offsets, cursor, dis,
                                                         csr_src, csr_w);

    int agg_grid = (N_NODES + 3) / 4;          // 4 nodes (waves) per block
    int gemm_grid = (N_NODES + 63) / 64;       // 782 blocks

    // layer 0 (reordered): ax = Â x; h_a = relu(ax @ W0 + b0)
    aggregate_x<<<agg_grid, 256, 0, stream>>>(x, offsets, csr_src, csr_w, dis, ax);
    gemm8x8<F_IN, true><<<gemm_grid, 128, 0, stream>>>(ax, W0, b0, h_a, N_NODES);
    // layer 1: h_b = relu(Â (h_a @ W1) + b1)
    gemm8x8<F_HID, false><<<gemm_grid, 128, 0, stream>>>(h_a, W1, nullptr, h_tmp, N_NODES);
    aggregate128<true><<<agg_grid, 256, 0, stream>>>(h_tmp, offsets, csr_src, csr_w, dis, b1, h_b);
    // layer 2: h_a = Â (h_b @ W2) + b2
    gemm8x8<F_HID, false><<<gemm_grid, 128, 0, stream>>>(h_b, W2, nullptr, h_tmp, N_NODES);
    aggregate128<false><<<agg_grid, 256, 0, stream>>>(h_tmp, offsets, csr_src, csr_w, dis, b2, h_a);

    // pool + MLP
    pool16<<<(N_NODES + 15) / 16, 128, 0, stream>>>(h_a, batch, g_acc, g_cnt);
    mlp1<<<N_GRAPHS, N_HID, 0, stream>>>(g_acc, g_cnt, Wm1, bm1, g_hid);
    mlp2<<<N_GRAPHS, N_OUT, 0, stream>>>(g_hid, Wm2, bm2, (float*)d_out);
}

// Round 6
// 452.978 us; speedup vs baseline: 1.4540x; 1.0055x over previous
//
#include <hip/hip_runtime.h>
#include <hip/hip_bf16.h>
#include <math.h>
#include <stdint.h>

#define N_NODES 50000
#define N_EDGES 800000
#define N_GRAPHS 256
#define F_IN 64
#define F_HID 128
#define N_HID 512
#define N_OUT 256

#define SCAN_B 256
#define SCAN_NBLK ((N_NODES + SCAN_B - 1) / SCAN_B)   // 196

// ---------------------------------------------------------------------------
// K1: in-degree count (edges only; self-loop added analytically later)
__global__ void count_deg(const int* __restrict__ ei, int* __restrict__ indeg) {
    int e = blockIdx.x * blockDim.x + threadIdx.x;
    if (e < N_EDGES) atomicAdd(&indeg[ei[N_EDGES + e]], 1);
}

// ---------------------------------------------------------------------------
// K2a: per-block reduction of indeg chunks -> blockSums
__global__ __launch_bounds__(SCAN_B) void scan_partial(const int* __restrict__ indeg,
                                                       int* __restrict__ blockSums) {
    __shared__ int sdata[SCAN_B];
    int i = blockIdx.x * SCAN_B + threadIdx.x;
    sdata[threadIdx.x] = (i < N_NODES) ? indeg[i] : 0;
    __syncthreads();
    for (int off = SCAN_B / 2; off > 0; off >>= 1) {
        if (threadIdx.x < off) sdata[threadIdx.x] += sdata[threadIdx.x + off];
        __syncthreads();
    }
    if (threadIdx.x == 0) blockSums[blockIdx.x] = sdata[0];
}

// K2b: single tiny block: exclusive scan of blockSums (SCAN_NBLK <= 256)
__global__ __launch_bounds__(SCAN_B) void scan_block_sums(int* __restrict__ blockSums) {
    __shared__ int buf[SCAN_B];
    int tid = threadIdx.x;
    int v = (tid < SCAN_NBLK) ? blockSums[tid] : 0;
    buf[tid] = v;
    __syncthreads();
    for (int off = 1; off < SCAN_B; off <<= 1) {
        int t = (tid >= off) ? buf[tid - off] : 0;
        __syncthreads();
        buf[tid] += t;
        __syncthreads();
    }
    if (tid < SCAN_NBLK) blockSums[tid] = buf[tid] - v;   // exclusive
}

// K2c: per-block exclusive scan + block offset -> offsets; also dis = rsqrt(deg+1)
__global__ __launch_bounds__(SCAN_B) void scan_final(const int* __restrict__ indeg,
                                                     const int* __restrict__ blockSums,
                                                     int* __restrict__ offsets,
                                                     float* __restrict__ dis) {
    __shared__ int buf[SCAN_B];
    int tid = threadIdx.x;
    int i = blockIdx.x * SCAN_B + tid;
    int v = (i < N_NODES) ? indeg[i] : 0;
    if (i < N_NODES) dis[i] = rsqrtf((float)(v + 1));
    buf[tid] = v;
    __syncthreads();
    for (int off = 1; off < SCAN_B; off <<= 1) {
        int t = (tid >= off) ? buf[tid - off] : 0;
        __syncthreads();
        buf[tid] += t;
        __syncthreads();
    }
    if (i < N_NODES) offsets[i] = blockSums[blockIdx.x] + buf[tid] - v;
    if (i == 0) offsets[N_NODES] = N_EDGES;   // total is statically known
}

// ---------------------------------------------------------------------------
// K3: scatter edges into CSR (by dst). Packed (src,w) -> one 8B store/edge.
__global__ void build_csr(const int* __restrict__ ei, const int* __restrict__ offsets,
                          int* __restrict__ cursor, const float* __restrict__ dis,
                          float2* __restrict__ csr) {
    int e = blockIdx.x * blockDim.x + threadIdx.x;
    if (e < N_EDGES) {
        int s = ei[e];
        int d = ei[N_EDGES + e];
        int pos = atomicAdd(&cursor[d], 1);
        csr[offsets[d] + pos] = make_float2(__int_as_float(s), dis[s] * dis[d]);
    }
}

// ---------------------------------------------------------------------------
// K4: C[M,128] = A[M,K] @ W[K,128]. 64x128 tile, 128 threads, 8x8/thread.
template <int K, bool BIASRELU>
__global__ __launch_bounds__(128) void gemm8x8(const float* __restrict__ A,
                                               const float* __restrict__ W,
                                               const float* __restrict__ bias,
                                               float* __restrict__ out, int M) {
    const int BM = 64, KC = 32, LDA = 36;
    __shared__ float As[BM * LDA];     // 9.2 KB
    __shared__ float Bs[KC * 128];     // 16 KB
    int tid = threadIdx.x;
    int tx = tid & 15;                 // cols tx*4 and 64+tx*4
    int ty = tid >> 4;                 // 0..7; rows ty + 8*i
    int row0 = blockIdx.x * BM;
    float acc[8][8] = {};
    for (int k0 = 0; k0 < K; k0 += KC) {
#pragma unroll
        for (int u = 0; u < 4; ++u) {
            int f4id = tid + 128 * u;
            int m = f4id >> 3;                 // 0..63
            int ks = (f4id & 7) * 4;           // 0,4,..28
            int r = row0 + m;
            float4 v = make_float4(0.f, 0.f, 0.f, 0.f);
            if (r < M) v = *(const float4*)&A[(size_t)r * K + k0 + ks];
            *(float4*)&As[m * LDA + ks] = v;
        }
#pragma unroll
        for (int u = 0; u < 8; ++u) {
            int f4id = tid + 128 * u;
            int kk = f4id >> 5;                // 0..31
            int n4 = (f4id & 31) * 4;          // 0..124
            *(float4*)&Bs[kk * 128 + n4] = *(const float4*)&W[(size_t)(k0 + kk) * 128 + n4];
        }
        __syncthreads();
#pragma unroll
        for (int kc = 0; kc < KC; kc += 4) {
            float4 av[8], bv0[4], bv1[4];
#pragma unroll
            for (int i = 0; i < 8; ++i)
                av[i] = *(const float4*)&As[(ty + 8 * i) * LDA + kc];
#pragma unroll
            for (int q = 0; q < 4; ++q) {
                bv0[q] = *(const float4*)&Bs[(kc + q) * 128 + tx * 4];
                bv1[q] = *(const float4*)&Bs[(kc + q) * 128 + 64 + tx * 4];
            }
#pragma unroll
            for (int q = 0; q < 4; ++q) {
#pragma unroll
                for (int i = 0; i < 8; ++i) {
                    float a = ((const float*)&av[i])[q];
                    acc[i][0] += a * bv0[q].x;  acc[i][1] += a * bv0[q].y;
                    acc[i][2] += a * bv0[q].z;  acc[i][3] += a * bv0[q].w;
                    acc[i][4] += a * bv1[q].x;  acc[i][5] += a * bv1[q].y;
                    acc[i][6] += a * bv1[q].z;  acc[i][7] += a * bv1[q].w;
                }
            }
        }
        __syncthreads();
    }
    int c0 = tx * 4, c1 = 64 + tx * 4;
#pragma unroll
    for (int i = 0; i < 8; ++i) {
        int r = row0 + ty + 8 * i;
        if (r < M) {
            float4 v0 = make_float4(acc[i][0], acc[i][1], acc[i][2], acc[i][3]);
            float4 v1 = make_float4(acc[i][4], acc[i][5], acc[i][6], acc[i][7]);
            if (BIASRELU) {
                v0.x = fmaxf(v0.x + bias[c0], 0.f);   v0.y = fmaxf(v0.y + bias[c0+1], 0.f);
                v0.z = fmaxf(v0.z + bias[c0+2], 0.f); v0.w = fmaxf(v0.w + bias[c0+3], 0.f);
                v1.x = fmaxf(v1.x + bias[c1], 0.f);   v1.y = fmaxf(v1.y + bias[c1+1], 0.f);
                v1.z = fmaxf(v1.z + bias[c1+2], 0.f); v1.w = fmaxf(v1.w + bias[c1+3], 0.f);
            }
            *(float4*)&out[(size_t)r * 128 + c0] = v0;
            *(float4*)&out[(size_t)r * 128 + c1] = v1;
        }
    }
}

// ---------------------------------------------------------------------------
// K5a: F=128 aggregate, float4 lanes: one wave = one node, but each gather
// instruction fetches TWO edge rows (lanes 0-31 edge A, 32-63 edge B).
// 8 insts in flight = 16 edges. Final xor-32 shuffle combines the halves.
template <bool RELU>
__global__ __launch_bounds__(256) void aggregate128(const float* __restrict__ h,
                                                    const int* __restrict__ offsets,
                                                    const float2* __restrict__ csr,
                                                    const float* __restrict__ dis,
                                                    const float* __restrict__ bias,
                                                    float* __restrict__ out) {
    int wave = threadIdx.x >> 6;
    int lane = threadIdx.x & 63;
    int i = blockIdx.x * 4 + wave;
    if (i >= N_NODES) return;
    int sub = lane >> 5;               // which edge of the pair
    int q   = lane & 31;               // float4 index within the 128-f row
    const float4* h4 = (const float4*)h;   // row stride = 32 float4
    float4 acc = make_float4(0.f, 0.f, 0.f, 0.f);
    int j = offsets[i], s1 = offsets[i + 1];
    for (; j < s1; j += 16) {
        int s[8]; float w[8];
#pragma unroll
        for (int u = 0; u < 8; ++u) {
            int e = j + 2 * u + sub;
            float2 c = (e < s1) ? csr[e] : make_float2(__int_as_float(0), 0.f);
            s[u] = __float_as_int(c.x);
            w[u] = c.y;
        }
        float4 r[8];
#pragma unroll
        for (int u = 0; u < 8; ++u) r[u] = h4[(size_t)s[u] * 32 + q];
#pragma unroll
        for (int u = 0; u < 8; ++u) {
            acc.x += w[u] * r[u].x;  acc.y += w[u] * r[u].y;
            acc.z += w[u] * r[u].z;  acc.w += w[u] * r[u].w;
        }
    }
    // combine the two half-wave partial sums (both halves end with the total)
    acc.x += __shfl_xor(acc.x, 32, 64);
    acc.y += __shfl_xor(acc.y, 32, 64);
    acc.z += __shfl_xor(acc.z, 32, 64);
    acc.w += __shfl_xor(acc.w, 32, 64);
    float dii = dis[i];
    float4 self = h4[(size_t)i * 32 + q];
    float4 b = ((const float4*)bias)[q];
    acc.x += dii * dii * self.x + b.x;
    acc.y += dii * dii * self.y + b.y;
    acc.z += dii * dii * self.z + b.z;
    acc.w += dii * dii * self.w + b.w;
    if (RELU) {
        acc.x = fmaxf(acc.x, 0.f); acc.y = fmaxf(acc.y, 0.f);
        acc.z = fmaxf(acc.z, 0.f); acc.w = fmaxf(acc.w, 0.f);
    }
    if (sub == 0) ((float4*)out)[(size_t)i * 32 + q] = acc;
}

// K5b: F=64 aggregate of raw x (layer-0 reorder). float4 lanes, FOUR edges
// per gather instruction (16 lanes per row). xor-16 + xor-32 combine.
__global__ __launch_bounds__(256) void aggregate_x(const float* __restrict__ x,
                                                   const int* __restrict__ offsets,
                                                   const float2* __restrict__ csr,
                                                   const float* __restrict__ dis,
                                                   float* __restrict__ out) {
    int wave = threadIdx.x >> 6;
    int lane = threadIdx.x & 63;
    int i = blockIdx.x * 4 + wave;
    if (i >= N_NODES) return;
    int sub = lane >> 4;               // 0..3: which edge of the quad
    int q   = lane & 15;               // float4 index within the 64-f row
    const float4* x4 = (const float4*)x;   // row stride = 16 float4
    float4 acc = make_float4(0.f, 0.f, 0.f, 0.f);
    int j = offsets[i], s1 = offsets[i + 1];
    for (; j < s1; j += 16) {
        int s[4]; float w[4];
#pragma unroll
        for (int u = 0; u < 4; ++u) {
            int e = j + 4 * u + sub;
            float2 c = (e < s1) ? csr[e] : make_float2(__int_as_float(0), 0.f);
            s[u] = __float_as_int(c.x);
            w[u] = c.y;
        }
        float4 r[4];
#pragma unroll
        for (int u = 0; u < 4; ++u) r[u] = x4[(size_t)s[u] * 16 + q];
#pragma unroll
        for (int u = 0; u < 4; ++u) {
            acc.x += w[u] * r[u].x;  acc.y += w[u] * r[u].y;
            acc.z += w[u] * r[u].z;  acc.w += w[u] * r[u].w;
        }
    }
    acc.x += __shfl_xor(acc.x, 16, 64);
    acc.y += __shfl_xor(acc.y, 16, 64);
    acc.z += __shfl_xor(acc.z, 16, 64);
    acc.w += __shfl_xor(acc.w, 16, 64);
    acc.x += __shfl_xor(acc.x, 32, 64);
    acc.y += __shfl_xor(acc.y, 32, 64);
    acc.z += __shfl_xor(acc.z, 32, 64);
    acc.w += __shfl_xor(acc.w, 32, 64);
    float dii = dis[i];
    float4 self = x4[(size_t)i * 16 + q];
    acc.x += dii * dii * self.x;
    acc.y += dii * dii * self.y;
    acc.z += dii * dii * self.z;
    acc.w += dii * dii * self.w;
    if (sub == 0) ((float4*)out)[(size_t)i * 16 + q] = acc;
}

// ---------------------------------------------------------------------------
// K6: mean-pool (batch is sorted -> register-accumulate 16 nodes, flush on change)
__global__ __launch_bounds__(128) void pool16(const float* __restrict__ h,
                                              const int* __restrict__ batch,
                                              float* __restrict__ g_acc,
                                              float* __restrict__ g_cnt) {
    const int NB = 16;
    int base = blockIdx.x * NB;
    int f = threadIdx.x;
    float acc = 0.f;
    int cur = -1, cnt = 0;
    for (int n = 0; n < NB; ++n) {
        int i = base + n;
        if (i >= N_NODES) break;
        int b = batch[i];
        if (b != cur) {
            if (cur >= 0) {
                atomicAdd(&g_acc[(size_t)cur * F_HID + f], acc);
                if (f == 0) atomicAdd(&g_cnt[cur], (float)cnt);
            }
            cur = b; acc = 0.f; cnt = 0;
        }
        acc += h[(size_t)i * F_HID + f];
        cnt++;
    }
    if (cur >= 0) {
        atomicAdd(&g_acc[(size_t)cur * F_HID + f], acc);
        if (f == 0) atomicAdd(&g_cnt[cur], (float)cnt);
    }
}

// ---------------------------------------------------------------------------
// K7: g_hid = relu((g_acc/cnt) @ Wm1 + bm1)   [256,128]@[128,512]
__global__ __launch_bounds__(512) void mlp1(const float* __restrict__ g_acc,
                                            const float* __restrict__ g_cnt,
                                            const float* __restrict__ Wm1,
                                            const float* __restrict__ bm1,
                                            float* __restrict__ g_hid) {
    __shared__ float row[F_HID];
    int g = blockIdx.x;
    int t = threadIdx.x;              // 0..511
    if (t < F_HID) {
        float c = g_cnt[g];
        row[t] = g_acc[(size_t)g * F_HID + t] / fmaxf(c, 1.0f);
    }
    __syncthreads();
    float acc = bm1[t];
    for (int k = 0; k < F_HID; ++k) acc += row[k] * Wm1[(size_t)k * N_HID + t];
    g_hid[(size_t)g * N_HID + t] = fmaxf(acc, 0.f);
}

// K8: out = g_hid @ Wm2 + bm2   [256,512]@[512,256]
__global__ __launch_bounds__(256) void mlp2(const float* __restrict__ g_hid,
                                            const float* __restrict__ Wm2,
                                            const float* __restrict__ bm2,
                                            float* __restrict__ out) {
    __shared__ float row[N_HID];
    int g = blockIdx.x;
    int t = threadIdx.x;              // 0..255
    row[t] = g_hid[(size_t)g * N_HID + t];
    row[t + 256] = g_hid[(size_t)g * N_HID + t + 256];
    __syncthreads();
    float acc = bm2[t];
    for (int k = 0; k < N_HID; ++k) acc += row[k] * Wm2[(size_t)k * N_OUT + t];
    out[(size_t)g * N_OUT + t] = acc;
}

// ---------------------------------------------------------------------------
extern "C" void kernel_launch(void* const* d_in, const int* in_sizes, int n_in,
                              void* d_out, int out_size, void* d_ws, size_t ws_size,
                              hipStream_t stream) {
    const float* x   = (const float*)d_in[0];
    const int* ei    = (const int*)d_in[1];     // [2, E] int32
    const int* batch = (const int*)d_in[2];
    const float* W0 = (const float*)d_in[3];  const float* b0 = (const float*)d_in[4];
    const float* W1 = (const float*)d_in[5];  const float* b1 = (const float*)d_in[6];
    const float* W2 = (const float*)d_in[7];  const float* b2 = (const float*)d_in[8];
    const float* Wm1 = (const float*)d_in[9];  const float* bm1 = (const float*)d_in[10];
    const float* Wm2 = (const float*)d_in[11]; const float* bm2 = (const float*)d_in[12];

    // bump allocator on d_ws, 256B-aligned slots
    char* p = (char*)d_ws;
    auto alloc = [&](size_t bytes) -> char* {
        char* r = p;
        p += (bytes + 255) & ~(size_t)255;
        return r;
    };
    // zero-init region (contiguous in allocation order)
    int*   indeg  = (int*)alloc(N_NODES * 4);
    int*   cursor = (int*)alloc(N_NODES * 4);
    float* g_acc  = (float*)alloc((size_t)N_GRAPHS * F_HID * 4);
    float* g_cnt  = (float*)alloc(N_GRAPHS * 4);
    size_t zero_bytes = (size_t)(p - (char*)indeg);
    // rest
    int*   blockSums = (int*)alloc(SCAN_NBLK * 4);
    int*   offsets = (int*)alloc((N_NODES + 1) * 4);
    float* dis     = (float*)alloc(N_NODES * 4);
    float2* csr    = (float2*)alloc((size_t)N_EDGES * 8);
    float* ax      = (float*)alloc((size_t)N_NODES * F_IN * 4);
    float* h_a     = (float*)alloc((size_t)N_NODES * F_HID * 4);
    float* h_tmp   = (float*)alloc((size_t)N_NODES * F_HID * 4);
    float* h_b     = (float*)alloc((size_t)N_NODES * F_HID * 4);
    float* g_hid   = (float*)alloc((size_t)N_GRAPHS * N_HID * 4);
    (void)ws_size; (void)in_sizes; (void)n_in; (void)out_size;

    hipMemsetAsync(indeg, 0, zero_bytes, stream);

    count_deg<<<(N_EDGES + 255) / 256, 256, 0, stream>>>(ei, indeg);
    scan_partial<<<SCAN_NBLK, SCAN_B, 0, stream>>>(indeg, blockSums);
    scan_block_sums<<<1, SCAN_B, 0, stream>>>(blockSums);
    scan_final<<<SCAN_NBLK, SCAN_B, 0, stream>>>(indeg, blockSums, offsets, dis);
    build_csr<<<(N_EDGES + 255) / 256, 256, 0, stream>>>(ei, offsets, cursor, dis, csr);

    int agg_grid = (N_NODES + 3) / 4;          // 4 nodes (waves) per block
    int gemm_grid = (N_NODES + 63) / 64;       // 782 blocks

    // layer 0 (reordered): ax = Â x; h_a = relu(ax @ W0 + b0)
    aggregate_x<<<agg_grid, 256, 0, stream>>>(x, offsets, csr, dis, ax);
    gemm8x8<F_IN, true><<<gemm_grid, 128, 0, stream>>>(ax, W0, b0, h_a, N_NODES);
    // layer 1: h_b = relu(Â (h_a @ W1) + b1)
    gemm8x8<F_HID, false><<<gemm_grid, 128, 0, stream>>>(h_a, W1, nullptr, h_tmp, N_NODES);
    aggregate128<true><<<agg_grid, 256, 0, stream>>>(h_tmp, offsets, csr, dis, b1, h_b);
    // layer 2: h_a = Â (h_b @ W2) + b2
    gemm8x8<F_HID, false><<<gemm_grid, 128, 0, stream>>>(h_b, W2, nullptr, h_tmp, N_NODES);
    aggregate128<false><<<agg_grid, 256, 0, stream>>>(h_tmp, offsets, csr, dis, b2, h_a);

    // pool + MLP
    pool16<<<(N_NODES + 15) / 16, 128, 0, stream>>>(h_a, batch, g_acc, g_cnt);
    mlp1<<<N_GRAPHS, N_HID, 0, stream>>>(g_acc, g_cnt, Wm1, bm1, g_hid);
    mlp2<<<N_GRAPHS, N_OUT, 0, stream>>>(g_hid, Wm2, bm2, (float*)d_out);
}